// Round 1
// baseline (1191.108 us; speedup 1.0000x reference)
//
#include <hip/hip_runtime.h>
#include <math.h>

#define T 512
#define B 128
#define KK 8
#define HH 32
#define PP 32

// ws layout (floats)
#define WS_GXF   0
#define WS_GXB   6291456
#define WS_HSEQ  12582912
#define WS_LOGITS 0            /* alias of GXF, used after GRU consumed gx */
#define WS_INIT  16777216
#define WS_YSEQ  16778240

// d_out layout (floats)
#define OUT_A    0
#define OUT_B    16777216
#define OUT_C    25165824
#define OUT_Q    58720256
#define OUT_LQ   75497472
#define OUT_LP   75563008

__device__ __forceinline__ float gmax8(float v) {
    v = fmaxf(v, __shfl_xor(v, 1, 64));
    v = fmaxf(v, __shfl_xor(v, 2, 64));
    v = fmaxf(v, __shfl_xor(v, 4, 64));
    return v;
}
__device__ __forceinline__ float gsum8(float v) {
    v += __shfl_xor(v, 1, 64);
    v += __shfl_xor(v, 2, 64);
    v += __shfl_xor(v, 4, 64);
    return v;
}

// ---------------- Kernel A: gx = x @ wih^T + bih (both directions) ----------
__global__ __launch_bounds__(256) void gx_kernel(
    const float* __restrict__ a_seq,
    const float* __restrict__ wih_f, const float* __restrict__ bih_f,
    const float* __restrict__ wih_b, const float* __restrict__ bih_b,
    float* __restrict__ gx_f, float* __restrict__ gx_b) {
    size_t idx = (size_t)blockIdx.x * blockDim.x + threadIdx.x;
    size_t total = (size_t)T * B * 192;
    if (idx >= total) return;
    int g192 = (int)(idx % 192);
    size_t tb = idx / 192;          // t*B + b
    int b = (int)(tb % B);
    int t = (int)(tb / B);
    int dir = g192 / 96;
    int g = g192 % 96;
    const float* w = dir ? wih_b : wih_f;
    const float* bb = dir ? bih_b : bih_f;
    const float4* x4 = (const float4*)(a_seq + ((size_t)b * T + t) * PP);
    const float4* w4 = (const float4*)(w + (size_t)g * PP);
    float acc = bb[g];
#pragma unroll
    for (int q = 0; q < 8; ++q) {
        float4 xv = x4[q];
        float4 wv = w4[q];
        acc = fmaf(xv.x, wv.x, acc);
        acc = fmaf(xv.y, wv.y, acc);
        acc = fmaf(xv.z, wv.z, acc);
        acc = fmaf(xv.w, wv.w, acc);
    }
    float* outp = dir ? gx_b : gx_f;
    outp[tb * 96 + g] = acc;
}

// ---------------- Kernel B: GRU scan, one wave per (batch, direction) -------
__global__ __launch_bounds__(64) void gru_kernel(
    const float* __restrict__ gx_f, const float* __restrict__ gx_b,
    const float* __restrict__ whh_f, const float* __restrict__ bhh_f,
    const float* __restrict__ whh_b, const float* __restrict__ bhh_b,
    float* __restrict__ hseq) {
    int cid = blockIdx.x;            // 0..255
    int b = cid >> 1;
    int dir = cid & 1;
    int lane = threadIdx.x;          // 0..63
    int i = lane & 31;
    int s = lane >> 5;
    int c0 = s * 16;
    const float* whh = dir ? whh_b : whh_f;
    const float* bhh = dir ? bhh_b : bhh_f;
    const float* gx = dir ? gx_b : gx_f;

    float wr[16], wz[16], wn[16];
#pragma unroll
    for (int jj = 0; jj < 16; ++jj) {
        wr[jj] = whh[(size_t)i * HH + c0 + jj];
        wz[jj] = whh[(size_t)(HH + i) * HH + c0 + jj];
        wn[jj] = whh[(size_t)(2 * HH + i) * HH + c0 + jj];
    }
    float bhr = bhh[i], bhz = bhh[HH + i], bhn = bhh[2 * HH + i];

    float h = 0.f;
    int tt = dir ? (T - 1) : 0;
    int step = dir ? -1 : 1;
    const float* row = gx + ((size_t)tt * B + b) * 96;
    float xr = row[i], xz = row[HH + i], xn = row[2 * HH + i];

    for (int tc = 0; tc < T; ++tc) {
        // prefetch next step's gx (independent of dep chain)
        float nxr = 0.f, nxz = 0.f, nxn = 0.f;
        int tn = tt + step;
        if (tc + 1 < T) {
            const float* rn = gx + ((size_t)tn * B + b) * 96;
            nxr = rn[i];
            nxz = rn[HH + i];
            nxn = rn[2 * HH + i];
        }
        float hr = 0.f, hz = 0.f, hn = 0.f;
#pragma unroll
        for (int jj = 0; jj < 16; ++jj) {
            float hj = __shfl(h, c0 + jj, 64);
            hr = fmaf(wr[jj], hj, hr);
            hz = fmaf(wz[jj], hj, hz);
            hn = fmaf(wn[jj], hj, hn);
        }
        hr += __shfl_xor(hr, 32, 64);
        hz += __shfl_xor(hz, 32, 64);
        hn += __shfl_xor(hn, 32, 64);
        float r = 1.f / (1.f + __expf(-(xr + hr + bhr)));
        float z = 1.f / (1.f + __expf(-(xz + hz + bhz)));
        float narg = xn + r * (hn + bhn);
        float e2 = __expf(-2.f * fabsf(narg));
        float n = copysignf((1.f - e2) / (1.f + e2), narg);
        h = (1.f - z) * n + z * h;
        if (s == 0) {
            hseq[((size_t)tt * B + b) * 64 + dir * HH + i] = h;
        }
        tt = tn;
        xr = nxr; xz = nxz; xn = nxn;
    }
}

// ---------------- Kernel C: logits = h_seq @ wl^T + bl (+ init_logits) ------
__global__ __launch_bounds__(64) void logits_kernel(
    const float* __restrict__ hseq,
    const float* __restrict__ wl, const float* __restrict__ bl,
    const float* __restrict__ wi, const float* __restrict__ bi,
    float* __restrict__ logits, float* __restrict__ initl) {
    int tb = blockIdx.x;   // t*B + b
    int g = threadIdx.x;   // 0..63
    __shared__ float hrow[64];
    hrow[g] = hseq[(size_t)tb * 64 + g];
    __syncthreads();
    float acc = bl[g];
    const float* wrow = wl + (size_t)g * 64;
#pragma unroll
    for (int c = 0; c < 64; ++c) acc = fmaf(wrow[c], hrow[c], acc);
    logits[(size_t)tb * 64 + g] = acc;
    if (tb < B && g < 8) {            // t == 0 blocks, tb == b
        float a2 = bi[g];
        const float* w2 = wi + (size_t)g * 64;
#pragma unroll
        for (int c = 0; c < 64; ++c) a2 = fmaf(w2[c], hrow[c], a2);
        initl[tb * 8 + g] = a2;
    }
}

// ---------------- Kernel D: gumbel-softmax scan, 8 lanes per batch ----------
__global__ __launch_bounds__(256) void gumbel_kernel(
    const float* __restrict__ logits, const float* __restrict__ initl,
    const float* __restrict__ u0, const float* __restrict__ useq,
    float* __restrict__ yseq, float* __restrict__ logq, float* __restrict__ logp) {
    const float TAU_INV = 2.0f;
    const float PSTAY = 0.9f;
    const float OFFV = (1.0f - 0.9f) / 7.0f;
    const float LOG_INV_K = -2.0794415416798357f;   // log(1/8)

    int tid = threadIdx.x;
    int lane = tid & 63;
    int j = tid & 7;
    int base = lane & 56;
    int b = blockIdx.x * 32 + (tid >> 3);
    if (b >= B) return;

    // t = 0
    float il = initl[b * 8 + j];
    float u = u0[b * 8 + j];
    float g0 = -logf(-logf(u));
    float a = (il + g0) * TAU_INV;
    float m = gmax8(a);
    float e = __expf(a - m);
    float se = gsum8(e);
    float y = e / se;
    float m2 = gmax8(il);
    float ee2 = __expf(il - m2);
    float se2 = gsum8(ee2);
    float lsm = il - m2 - logf(se2);
    float lq = gsum8(y * lsm);
    float sy = gsum8(y);
    float lp = LOG_INV_K * sy;
    yseq[((size_t)b * T + 0) * 8 + j] = y;
    if (j == 0) {
        logq[(size_t)b * T + 0] = lq;
        logp[(size_t)b * T + 0] = lp;
    }

    for (int t = 1; t < T; ++t) {
        const float* lrow = logits + ((size_t)t * B + b) * 64;
        float l = 0.f;
#pragma unroll
        for (int k = 0; k < 8; ++k) {
            l = fmaf(__shfl(y, base + k, 64), lrow[k * 8 + j], l);
        }
        float uu = useq[((size_t)b * (T - 1) + (t - 1)) * 8 + j];
        float gg = -logf(-logf(uu));
        float aa = (l + gg) * TAU_INV;
        float mm = gmax8(aa);
        float ex = __expf(aa - mm);
        float ses = gsum8(ex);
        float yn = ex / ses;
        float lm2 = gmax8(l);
        float le2 = __expf(l - lm2);
        float lse2 = gsum8(le2);
        float lsm2 = l - lm2 - logf(lse2);
        float lqv = gsum8(yn * lsm2);
        float syv = gsum8(y);
        float tp = OFFV * syv + (PSTAY - OFFV) * y;
        float lpv = gsum8(yn * logf(fmaxf(tp, 1e-8f)));
        yseq[((size_t)b * T + t) * 8 + j] = yn;
        if (j == 0) {
            logq[(size_t)b * T + t] = lqv;
            logp[(size_t)b * T + t] = lpv;
        }
        y = yn;
    }
}

// ---------------- Kernel E: output einsums + C broadcast (float4 stores) ----
__global__ __launch_bounds__(128) void out_kernel(
    const float* __restrict__ yseq,
    const float* __restrict__ A, const float* __restrict__ Bm,
    const float* __restrict__ C, const float* __restrict__ Q,
    float4* __restrict__ out4) {
    int bt = blockIdx.x;   // b*T + t
    __shared__ float ys[8];
    if (threadIdx.x < 8) ys[threadIdx.x] = yseq[(size_t)bt * 8 + threadIdx.x];
    __syncthreads();
    float yr[8];
#pragma unroll
    for (int k = 0; k < 8; ++k) yr[k] = ys[k];

    const float4* A4 = (const float4*)A;
    const float4* B4 = (const float4*)Bm;
    const float4* Q4 = (const float4*)Q;
    const float4* C4 = (const float4*)C;

    for (int q = threadIdx.x; q < 288; q += 128) {
        float4 v = make_float4(0.f, 0.f, 0.f, 0.f);
        size_t oidx;
        if (q < 64) {
#pragma unroll
            for (int k = 0; k < 8; ++k) {
                float4 w = A4[k * 64 + q];
                v.x = fmaf(yr[k], w.x, v.x);
                v.y = fmaf(yr[k], w.y, v.y);
                v.z = fmaf(yr[k], w.z, v.z);
                v.w = fmaf(yr[k], w.w, v.w);
            }
            oidx = (size_t)(OUT_A / 4) + (size_t)bt * 64 + q;
        } else if (q < 96) {
            int qb = q - 64;
#pragma unroll
            for (int k = 0; k < 8; ++k) {
                float4 w = B4[k * 32 + qb];
                v.x = fmaf(yr[k], w.x, v.x);
                v.y = fmaf(yr[k], w.y, v.y);
                v.z = fmaf(yr[k], w.z, v.z);
                v.w = fmaf(yr[k], w.w, v.w);
            }
            oidx = (size_t)(OUT_B / 4) + (size_t)bt * 32 + qb;
        } else if (q < 160) {
            int qq = q - 96;
#pragma unroll
            for (int k = 0; k < 8; ++k) {
                float4 w = Q4[k * 64 + qq];
                v.x = fmaf(yr[k], w.x, v.x);
                v.y = fmaf(yr[k], w.y, v.y);
                v.z = fmaf(yr[k], w.z, v.z);
                v.w = fmaf(yr[k], w.w, v.w);
            }
            oidx = (size_t)(OUT_Q / 4) + (size_t)bt * 64 + qq;
        } else {
            int qc = q - 160;
            v = C4[qc];
            oidx = (size_t)(OUT_C / 4) + (size_t)bt * 128 + qc;
        }
        out4[oidx] = v;
    }
}

extern "C" void kernel_launch(void* const* d_in, const int* in_sizes, int n_in,
                              void* d_out, int out_size, void* d_ws, size_t ws_size,
                              hipStream_t stream) {
    const float* a_seq = (const float*)d_in[0];
    const float* A     = (const float*)d_in[1];
    const float* Bmat  = (const float*)d_in[2];
    const float* C     = (const float*)d_in[3];
    const float* Q     = (const float*)d_in[4];
    const float* wih_f = (const float*)d_in[5];
    const float* whh_f = (const float*)d_in[6];
    const float* bih_f = (const float*)d_in[7];
    const float* bhh_f = (const float*)d_in[8];
    const float* wih_b = (const float*)d_in[9];
    const float* whh_b = (const float*)d_in[10];
    const float* bih_b = (const float*)d_in[11];
    const float* bhh_b = (const float*)d_in[12];
    const float* wl    = (const float*)d_in[13];
    const float* bl    = (const float*)d_in[14];
    const float* wi    = (const float*)d_in[15];
    const float* bi    = (const float*)d_in[16];
    const float* u0    = (const float*)d_in[17];
    const float* useq  = (const float*)d_in[18];

    float* ws = (float*)d_ws;
    float* gx_f   = ws + WS_GXF;
    float* gx_b   = ws + WS_GXB;
    float* hseq   = ws + WS_HSEQ;
    float* logits = ws + WS_LOGITS;   // aliases gx_f (gx consumed before C runs)
    float* initl  = ws + WS_INIT;
    float* yseq   = ws + WS_YSEQ;

    float* outf = (float*)d_out;
    float* logq = outf + OUT_LQ;
    float* logp = outf + OUT_LP;

    {
        size_t total = (size_t)T * B * 192;
        int blk = 256;
        int grid = (int)((total + blk - 1) / blk);
        gx_kernel<<<grid, blk, 0, stream>>>(a_seq, wih_f, bih_f, wih_b, bih_b, gx_f, gx_b);
    }
    gru_kernel<<<256, 64, 0, stream>>>(gx_f, gx_b, whh_f, bhh_f, whh_b, bhh_b, hseq);
    logits_kernel<<<T * B, 64, 0, stream>>>(hseq, wl, bl, wi, bi, logits, initl);
    gumbel_kernel<<<4, 256, 0, stream>>>(logits, initl, u0, useq, yseq, logq, logp);
    out_kernel<<<B * T, 128, 0, stream>>>(yseq, A, Bmat, C, Q, (float4*)d_out);
}

// Round 2
// 1162.676 us; speedup vs baseline: 1.0245x; 1.0245x over previous
//
#include <hip/hip_runtime.h>
#include <math.h>

#define T 512
#define B 128
#define KK 8
#define HH 32
#define PP 32

// ws layout (floats)
#define WS_GXF   0
#define WS_GXB   6291456
#define WS_GS    6291456       /* alias gx_b: gumbel noise, written after GRU consumed gx_b */
#define WS_HSEQ  12582912
#define WS_LOGITS 0            /* alias of GXF, used after GRU consumed gx_f */
#define WS_INIT  16777216
#define WS_YSEQ  16778240

// d_out layout (floats)
#define OUT_A    0
#define OUT_B    16777216
#define OUT_C    25165824
#define OUT_Q    58720256
#define OUT_LQ   75497472
#define OUT_LP   75563008

#define TINV 2.0f
#define PSTAY 0.9f
#define OFFV (0.1f / 7.0f)
#define DPS (PSTAY - OFFV)
#define LOG_INV_K (-2.0794415416798357f)

// ---------------- Kernel A: gx = x @ wih^T + bih (both directions) ----------
__global__ __launch_bounds__(256) void gx_kernel(
    const float* __restrict__ a_seq,
    const float* __restrict__ wih_f, const float* __restrict__ bih_f,
    const float* __restrict__ wih_b, const float* __restrict__ bih_b,
    float* __restrict__ gx_f, float* __restrict__ gx_b) {
    size_t idx = (size_t)blockIdx.x * blockDim.x + threadIdx.x;
    size_t total = (size_t)T * B * 192;
    if (idx >= total) return;
    int g192 = (int)(idx % 192);
    size_t tb = idx / 192;          // t*B + b
    int b = (int)(tb % B);
    int t = (int)(tb / B);
    int dir = g192 / 96;
    int g = g192 % 96;
    const float* w = dir ? wih_b : wih_f;
    const float* bb = dir ? bih_b : bih_f;
    const float4* x4 = (const float4*)(a_seq + ((size_t)b * T + t) * PP);
    const float4* w4 = (const float4*)(w + (size_t)g * PP);
    float acc = bb[g];
#pragma unroll
    for (int q = 0; q < 8; ++q) {
        float4 xv = x4[q];
        float4 wv = w4[q];
        acc = fmaf(xv.x, wv.x, acc);
        acc = fmaf(xv.y, wv.y, acc);
        acc = fmaf(xv.z, wv.z, acc);
        acc = fmaf(xv.w, wv.w, acc);
    }
    float* outp = dir ? gx_b : gx_f;
    outp[tb * 96 + g] = acc;
}

// ---------------- Kernel B: GRU scan, one wave per (batch, direction) -------
__global__ __launch_bounds__(64) void gru_kernel(
    const float* __restrict__ gx_f, const float* __restrict__ gx_b,
    const float* __restrict__ whh_f, const float* __restrict__ bhh_f,
    const float* __restrict__ whh_b, const float* __restrict__ bhh_b,
    float* __restrict__ hseq) {
    int cid = blockIdx.x;            // 0..255
    int b = cid >> 1;
    int dir = cid & 1;
    int lane = threadIdx.x;          // 0..63
    int i = lane & 31;
    int s = lane >> 5;
    int c0 = s * 16;
    const float* whh = dir ? whh_b : whh_f;
    const float* bhh = dir ? bhh_b : bhh_f;
    const float* gx = dir ? gx_b : gx_f;

    float wr[16], wz[16], wn[16];
#pragma unroll
    for (int jj = 0; jj < 16; ++jj) {
        wr[jj] = whh[(size_t)i * HH + c0 + jj];
        wz[jj] = whh[(size_t)(HH + i) * HH + c0 + jj];
        wn[jj] = whh[(size_t)(2 * HH + i) * HH + c0 + jj];
    }
    float bhr = bhh[i], bhz = bhh[HH + i], bhn = bhh[2 * HH + i];

    float h = 0.f;
    int tt = dir ? (T - 1) : 0;
    int step = dir ? -1 : 1;
    const float* row = gx + ((size_t)tt * B + b) * 96;
    float xr = row[i], xz = row[HH + i], xn = row[2 * HH + i];

    for (int tc = 0; tc < T; ++tc) {
        float nxr = 0.f, nxz = 0.f, nxn = 0.f;
        int tn = tt + step;
        if (tc + 1 < T) {
            const float* rn = gx + ((size_t)tn * B + b) * 96;
            nxr = rn[i];
            nxz = rn[HH + i];
            nxn = rn[2 * HH + i];
        }
        float hr = 0.f, hz = 0.f, hn = 0.f;
#pragma unroll
        for (int jj = 0; jj < 16; ++jj) {
            float hj = __shfl(h, c0 + jj, 64);
            hr = fmaf(wr[jj], hj, hr);
            hz = fmaf(wz[jj], hj, hz);
            hn = fmaf(wn[jj], hj, hn);
        }
        hr += __shfl_xor(hr, 32, 64);
        hz += __shfl_xor(hz, 32, 64);
        hn += __shfl_xor(hn, 32, 64);
        float r = 1.f / (1.f + __expf(-(xr + hr + bhr)));
        float z = 1.f / (1.f + __expf(-(xz + hz + bhz)));
        float narg = xn + r * (hn + bhn);
        float e2 = __expf(-2.f * fabsf(narg));
        float n = copysignf((1.f - e2) / (1.f + e2), narg);
        h = (1.f - z) * n + z * h;
        if (s == 0) {
            hseq[((size_t)tt * B + b) * 64 + dir * HH + i] = h;
        }
        tt = tn;
        xr = nxr; xz = nxz; xn = nxn;
    }
}

// ---------------- Kernel C: logits = h_seq @ wl^T + bl (+ init_logits) ------
__global__ __launch_bounds__(64) void logits_kernel(
    const float* __restrict__ hseq,
    const float* __restrict__ wl, const float* __restrict__ bl,
    const float* __restrict__ wi, const float* __restrict__ bi,
    float* __restrict__ logits, float* __restrict__ initl) {
    int tb = blockIdx.x;   // t*B + b
    int g = threadIdx.x;   // 0..63
    __shared__ float hrow[64];
    hrow[g] = hseq[(size_t)tb * 64 + g];
    __syncthreads();
    float acc = bl[g];
    const float* wrow = wl + (size_t)g * 64;
#pragma unroll
    for (int c = 0; c < 64; ++c) acc = fmaf(wrow[c], hrow[c], acc);
    logits[(size_t)tb * 64 + g] = acc;
    if (tb < B && g < 8) {            // t == 0 blocks, tb == b
        float a2 = bi[g];
        const float* w2 = wi + (size_t)g * 64;
#pragma unroll
        for (int c = 0; c < 64; ++c) a2 = fmaf(w2[c], hrow[c], a2);
        initl[tb * 8 + g] = a2;
    }
}

// ---------------- Kernel G: gumbel noise precompute, pre-scaled by 1/tau ----
// gs[b][t][8] = -log(-log(u)) / tau ; t=0 from u0, t>=1 from useq[b][t-1]
__global__ __launch_bounds__(256) void gsc_kernel(
    const float* __restrict__ u0, const float* __restrict__ useq,
    float* __restrict__ gs) {
    int tid = blockIdx.x * 256 + threadIdx.x;
    if (tid >= B * T * KK) return;
    int j = tid & 7;
    int t = (tid >> 3) & (T - 1);
    int b = tid >> 12;                // / (T*8)
    float u = (t == 0) ? u0[b * 8 + j]
                       : useq[((size_t)b * (T - 1) + (t - 1)) * 8 + j];
    gs[tid] = -logf(-logf(u)) * TINV;   // precise logf: u near 1 is ill-conditioned
}

// ---------------- softmax-8 helpers (per-lane serial) -----------------------
__device__ __forceinline__ void softmax8(const float (&a)[8], float (&y)[8]) {
    float m = fmaxf(fmaxf(fmaxf(a[0], a[1]), fmaxf(a[2], a[3])),
                    fmaxf(fmaxf(a[4], a[5]), fmaxf(a[6], a[7])));
    float e[8];
#pragma unroll
    for (int j = 0; j < 8; ++j) e[j] = __expf(a[j] - m);
    float s = ((e[0] + e[1]) + (e[2] + e[3])) + ((e[4] + e[5]) + (e[6] + e[7]));
    float r = 1.0f / s;
#pragma unroll
    for (int j = 0; j < 8; ++j) y[j] = e[j] * r;
}

__device__ __forceinline__ void gum_step(const float4 (&L)[16], const float4& ga,
                                         const float4& gb, float (&y)[8]) {
    float l[8];
#pragma unroll
    for (int j = 0; j < 8; ++j) l[j] = 0.f;
#pragma unroll
    for (int k = 0; k < 8; ++k) {
        float4 w0 = L[2 * k], w1 = L[2 * k + 1];
        float yk = y[k];
        l[0] = fmaf(yk, w0.x, l[0]); l[1] = fmaf(yk, w0.y, l[1]);
        l[2] = fmaf(yk, w0.z, l[2]); l[3] = fmaf(yk, w0.w, l[3]);
        l[4] = fmaf(yk, w1.x, l[4]); l[5] = fmaf(yk, w1.y, l[5]);
        l[6] = fmaf(yk, w1.z, l[6]); l[7] = fmaf(yk, w1.w, l[7]);
    }
    float a[8];
    a[0] = fmaf(l[0], TINV, ga.x); a[1] = fmaf(l[1], TINV, ga.y);
    a[2] = fmaf(l[2], TINV, ga.z); a[3] = fmaf(l[3], TINV, ga.w);
    a[4] = fmaf(l[4], TINV, gb.x); a[5] = fmaf(l[5], TINV, gb.y);
    a[6] = fmaf(l[6], TINV, gb.z); a[7] = fmaf(l[7], TINV, gb.w);
    softmax8(a, y);
}

// ---------------- Kernel D: y-only scan, lane = batch (2 waves total) -------
__global__ __launch_bounds__(64) void scan_kernel(
    const float* __restrict__ logits, const float* __restrict__ initl,
    const float* __restrict__ gs, float* __restrict__ yseq) {
    int b = blockIdx.x * 64 + threadIdx.x;   // grid = 2
    const float4* gp = (const float4*)(gs + (size_t)b * T * 8);
    float4* yp = (float4*)(yseq + (size_t)b * T * 8);

    float4 LA[16], LB[16];
    float4 gA0, gA1, gB0, gB1;

    // prefetch logits/noise for t=1 and t=2
    {
        const float4* L1 = (const float4*)(logits + ((size_t)1 * B + b) * 64);
        const float4* L2 = (const float4*)(logits + ((size_t)2 * B + b) * 64);
#pragma unroll
        for (int q = 0; q < 16; ++q) LA[q] = L1[q];
        gA0 = gp[2]; gA1 = gp[3];
#pragma unroll
        for (int q = 0; q < 16; ++q) LB[q] = L2[q];
        gB0 = gp[4]; gB1 = gp[5];
    }

    // t = 0: softmax((init_logits + g0)/tau)
    float y[8];
    {
        const float4* il4 = (const float4*)(initl + b * 8);
        float4 i0 = il4[0], i1 = il4[1];
        float4 g00 = gp[0], g01 = gp[1];
        float a[8];
        a[0] = fmaf(i0.x, TINV, g00.x); a[1] = fmaf(i0.y, TINV, g00.y);
        a[2] = fmaf(i0.z, TINV, g00.z); a[3] = fmaf(i0.w, TINV, g00.w);
        a[4] = fmaf(i1.x, TINV, g01.x); a[5] = fmaf(i1.y, TINV, g01.y);
        a[6] = fmaf(i1.z, TINV, g01.z); a[7] = fmaf(i1.w, TINV, g01.w);
        softmax8(a, y);
        yp[0] = make_float4(y[0], y[1], y[2], y[3]);
        yp[1] = make_float4(y[4], y[5], y[6], y[7]);
    }

    for (int t = 1; t < T; t += 2) {
        // step t with buffer A, then re-arm A for t+2
        gum_step(LA, gA0, gA1, y);
        yp[2 * t]     = make_float4(y[0], y[1], y[2], y[3]);
        yp[2 * t + 1] = make_float4(y[4], y[5], y[6], y[7]);
        {
            int tp = (t + 2 < T) ? (t + 2) : (T - 1);
            const float4* Lp = (const float4*)(logits + ((size_t)tp * B + b) * 64);
#pragma unroll
            for (int q = 0; q < 16; ++q) LA[q] = Lp[q];
            gA0 = gp[2 * tp]; gA1 = gp[2 * tp + 1];
        }
        if (t + 1 < T) {
            gum_step(LB, gB0, gB1, y);
            yp[2 * (t + 1)]     = make_float4(y[0], y[1], y[2], y[3]);
            yp[2 * (t + 1) + 1] = make_float4(y[4], y[5], y[6], y[7]);
            int tq = (t + 3 < T) ? (t + 3) : (T - 1);
            const float4* Lq = (const float4*)(logits + ((size_t)tq * B + b) * 64);
#pragma unroll
            for (int q = 0; q < 16; ++q) LB[q] = Lq[q];
            gB0 = gp[2 * tq]; gB1 = gp[2 * tq + 1];
        }
    }
}

// ---------------- Kernel E: parallel log_q / log_p --------------------------
__global__ __launch_bounds__(256) void lqlp_kernel(
    const float* __restrict__ logits, const float* __restrict__ initl,
    const float* __restrict__ yseq,
    float* __restrict__ logq, float* __restrict__ logp) {
    int tid = blockIdx.x * 256 + threadIdx.x;   // tid = b*T + t
    if (tid >= B * T) return;
    int b = tid >> 9;
    int t = tid & (T - 1);

    const float4* yt4 = (const float4*)(yseq + (size_t)tid * 8);
    float4 y0 = yt4[0], y1 = yt4[1];
    float yt[8] = {y0.x, y0.y, y0.z, y0.w, y1.x, y1.y, y1.z, y1.w};

    float l[8];
    float lp;
    if (t == 0) {
        const float4* il4 = (const float4*)(initl + b * 8);
        float4 i0 = il4[0], i1 = il4[1];
        l[0] = i0.x; l[1] = i0.y; l[2] = i0.z; l[3] = i0.w;
        l[4] = i1.x; l[5] = i1.y; l[6] = i1.z; l[7] = i1.w;
        float sy = ((yt[0] + yt[1]) + (yt[2] + yt[3])) + ((yt[4] + yt[5]) + (yt[6] + yt[7]));
        lp = LOG_INV_K * sy;
    } else {
        const float4* yp4 = (const float4*)(yseq + (size_t)(tid - 1) * 8);
        float4 p0 = yp4[0], p1 = yp4[1];
        float ypv[8] = {p0.x, p0.y, p0.z, p0.w, p1.x, p1.y, p1.z, p1.w};
        const float4* L4 = (const float4*)(logits + ((size_t)t * B + b) * 64);
#pragma unroll
        for (int j = 0; j < 8; ++j) l[j] = 0.f;
#pragma unroll
        for (int k = 0; k < 8; ++k) {
            float4 w0 = L4[2 * k], w1 = L4[2 * k + 1];
            float yk = ypv[k];
            l[0] = fmaf(yk, w0.x, l[0]); l[1] = fmaf(yk, w0.y, l[1]);
            l[2] = fmaf(yk, w0.z, l[2]); l[3] = fmaf(yk, w0.w, l[3]);
            l[4] = fmaf(yk, w1.x, l[4]); l[5] = fmaf(yk, w1.y, l[5]);
            l[6] = fmaf(yk, w1.z, l[6]); l[7] = fmaf(yk, w1.w, l[7]);
        }
        float sy = ((ypv[0] + ypv[1]) + (ypv[2] + ypv[3])) + ((ypv[4] + ypv[5]) + (ypv[6] + ypv[7]));
        float acc = 0.f;
#pragma unroll
        for (int j = 0; j < 8; ++j) {
            float tp = fmaf(DPS, ypv[j], OFFV * sy);
            acc = fmaf(yt[j], logf(fmaxf(tp, 1e-8f)), acc);
        }
        lp = acc;
    }
    // lq = sum yt * log_softmax(l)
    float m = fmaxf(fmaxf(fmaxf(l[0], l[1]), fmaxf(l[2], l[3])),
                    fmaxf(fmaxf(l[4], l[5]), fmaxf(l[6], l[7])));
    float se = 0.f;
#pragma unroll
    for (int j = 0; j < 8; ++j) se += __expf(l[j] - m);
    float lse = m + logf(se);
    float lq = 0.f;
#pragma unroll
    for (int j = 0; j < 8; ++j) lq = fmaf(yt[j], l[j] - lse, lq);
    logq[tid] = lq;
    logp[tid] = lp;
}

// ---------------- Kernel F: output einsums + C broadcast (float4 stores) ----
__global__ __launch_bounds__(128) void out_kernel(
    const float* __restrict__ yseq,
    const float* __restrict__ A, const float* __restrict__ Bm,
    const float* __restrict__ C, const float* __restrict__ Q,
    float4* __restrict__ out4) {
    int bt = blockIdx.x;   // b*T + t
    __shared__ float ys[8];
    if (threadIdx.x < 8) ys[threadIdx.x] = yseq[(size_t)bt * 8 + threadIdx.x];
    __syncthreads();
    float yr[8];
#pragma unroll
    for (int k = 0; k < 8; ++k) yr[k] = ys[k];

    const float4* A4 = (const float4*)A;
    const float4* B4 = (const float4*)Bm;
    const float4* Q4 = (const float4*)Q;
    const float4* C4 = (const float4*)C;

    for (int q = threadIdx.x; q < 288; q += 128) {
        float4 v = make_float4(0.f, 0.f, 0.f, 0.f);
        size_t oidx;
        if (q < 64) {
#pragma unroll
            for (int k = 0; k < 8; ++k) {
                float4 w = A4[k * 64 + q];
                v.x = fmaf(yr[k], w.x, v.x);
                v.y = fmaf(yr[k], w.y, v.y);
                v.z = fmaf(yr[k], w.z, v.z);
                v.w = fmaf(yr[k], w.w, v.w);
            }
            oidx = (size_t)(OUT_A / 4) + (size_t)bt * 64 + q;
        } else if (q < 96) {
            int qb = q - 64;
#pragma unroll
            for (int k = 0; k < 8; ++k) {
                float4 w = B4[k * 32 + qb];
                v.x = fmaf(yr[k], w.x, v.x);
                v.y = fmaf(yr[k], w.y, v.y);
                v.z = fmaf(yr[k], w.z, v.z);
                v.w = fmaf(yr[k], w.w, v.w);
            }
            oidx = (size_t)(OUT_B / 4) + (size_t)bt * 32 + qb;
        } else if (q < 160) {
            int qq = q - 96;
#pragma unroll
            for (int k = 0; k < 8; ++k) {
                float4 w = Q4[k * 64 + qq];
                v.x = fmaf(yr[k], w.x, v.x);
                v.y = fmaf(yr[k], w.y, v.y);
                v.z = fmaf(yr[k], w.z, v.z);
                v.w = fmaf(yr[k], w.w, v.w);
            }
            oidx = (size_t)(OUT_Q / 4) + (size_t)bt * 64 + qq;
        } else {
            int qc = q - 160;
            v = C4[qc];
            oidx = (size_t)(OUT_C / 4) + (size_t)bt * 128 + qc;
        }
        out4[oidx] = v;
    }
}

extern "C" void kernel_launch(void* const* d_in, const int* in_sizes, int n_in,
                              void* d_out, int out_size, void* d_ws, size_t ws_size,
                              hipStream_t stream) {
    const float* a_seq = (const float*)d_in[0];
    const float* A     = (const float*)d_in[1];
    const float* Bmat  = (const float*)d_in[2];
    const float* C     = (const float*)d_in[3];
    const float* Q     = (const float*)d_in[4];
    const float* wih_f = (const float*)d_in[5];
    const float* whh_f = (const float*)d_in[6];
    const float* bih_f = (const float*)d_in[7];
    const float* bhh_f = (const float*)d_in[8];
    const float* wih_b = (const float*)d_in[9];
    const float* whh_b = (const float*)d_in[10];
    const float* bih_b = (const float*)d_in[11];
    const float* bhh_b = (const float*)d_in[12];
    const float* wl    = (const float*)d_in[13];
    const float* bl    = (const float*)d_in[14];
    const float* wi    = (const float*)d_in[15];
    const float* bi    = (const float*)d_in[16];
    const float* u0    = (const float*)d_in[17];
    const float* useq  = (const float*)d_in[18];

    float* ws = (float*)d_ws;
    float* gx_f   = ws + WS_GXF;
    float* gx_b   = ws + WS_GXB;
    float* gsb    = ws + WS_GS;       // aliases gx_b (written after GRU)
    float* hseq   = ws + WS_HSEQ;
    float* logits = ws + WS_LOGITS;   // aliases gx_f (written after GRU)
    float* initl  = ws + WS_INIT;
    float* yseq   = ws + WS_YSEQ;

    float* outf = (float*)d_out;
    float* logq = outf + OUT_LQ;
    float* logp = outf + OUT_LP;

    {
        size_t total = (size_t)T * B * 192;
        int blk = 256;
        int grid = (int)((total + blk - 1) / blk);
        gx_kernel<<<grid, blk, 0, stream>>>(a_seq, wih_f, bih_f, wih_b, bih_b, gx_f, gx_b);
    }
    gru_kernel<<<256, 64, 0, stream>>>(gx_f, gx_b, whh_f, bhh_f, whh_b, bhh_b, hseq);
    {
        int total = B * T * KK;
        gsc_kernel<<<(total + 255) / 256, 256, 0, stream>>>(u0, useq, gsb);
    }
    logits_kernel<<<T * B, 64, 0, stream>>>(hseq, wl, bl, wi, bi, logits, initl);
    scan_kernel<<<2, 64, 0, stream>>>(logits, initl, gsb, yseq);
    lqlp_kernel<<<(B * T + 255) / 256, 256, 0, stream>>>(logits, initl, yseq, logq, logp);
    out_kernel<<<B * T, 128, 0, stream>>>(yseq, A, Bmat, C, Q, (float4*)d_out);
}

// Round 3
// 969.563 us; speedup vs baseline: 1.2285x; 1.1992x over previous
//
#include <hip/hip_runtime.h>
#include <math.h>

#define T 512
#define B 128
#define KK 8
#define HH 32
#define PP 32

// ws layout (floats)
#define WS_GXF   0
#define WS_GXB   6291456
#define WS_GS    6291456       /* alias gx_b: gumbel noise [t][b][8], written after GRU */
#define WS_HSEQ  12582912
#define WS_LOGITS 0            /* alias gx_f: scaled logits [t][b][64], written after GRU */
#define WS_INIT  16777216
#define WS_YSEQ  16778240

// d_out layout (floats)
#define OUT_A    0
#define OUT_B    16777216
#define OUT_C    25165824
#define OUT_Q    58720256
#define OUT_LQ   75497472
#define OUT_LP   75563008

#define TINV 2.0f
#define PSTAY 0.9f
#define OFFV (0.1f / 7.0f)
#define DPS (PSTAY - OFFV)
#define LOG_INV_K (-2.0794415416798357f)

typedef float f4v __attribute__((ext_vector_type(4)));
typedef __attribute__((address_space(3))) float as3f;

// async DMA global->LDS, 16B/lane, opaque to compiler (no auto waitcnt insertion)
__device__ __forceinline__ void dma16(unsigned ldsbyte, int voffbyte, const void* sbase) {
    asm volatile("s_mov_b32 m0, %0\n\t"
                 "global_load_lds_dwordx4 %1, %2"
                 :: "s"(ldsbyte), "v"(voffbyte), "s"(sbase)
                 : "memory");
}
// counted store (kept in asm so the per-iter vmcnt bookkeeping is exact)
__device__ __forceinline__ void st16(void* p, f4v v) {
    asm volatile("global_store_dwordx4 %0, %1, off" :: "v"(p), "v"(v) : "memory");
}

// ---------------- Kernel A: gx = x @ wih^T + bih (both directions) ----------
__global__ __launch_bounds__(256) void gx_kernel(
    const float* __restrict__ a_seq,
    const float* __restrict__ wih_f, const float* __restrict__ bih_f,
    const float* __restrict__ wih_b, const float* __restrict__ bih_b,
    float* __restrict__ gx_f, float* __restrict__ gx_b) {
    size_t idx = (size_t)blockIdx.x * blockDim.x + threadIdx.x;
    size_t total = (size_t)T * B * 192;
    if (idx >= total) return;
    int g192 = (int)(idx % 192);
    size_t tb = idx / 192;          // t*B + b
    int b = (int)(tb % B);
    int t = (int)(tb / B);
    int dir = g192 / 96;
    int g = g192 % 96;
    const float* w = dir ? wih_b : wih_f;
    const float* bb = dir ? bih_b : bih_f;
    const float4* x4 = (const float4*)(a_seq + ((size_t)b * T + t) * PP);
    const float4* w4 = (const float4*)(w + (size_t)g * PP);
    float acc = bb[g];
#pragma unroll
    for (int q = 0; q < 8; ++q) {
        float4 xv = x4[q];
        float4 wv = w4[q];
        acc = fmaf(xv.x, wv.x, acc);
        acc = fmaf(xv.y, wv.y, acc);
        acc = fmaf(xv.z, wv.z, acc);
        acc = fmaf(xv.w, wv.w, acc);
    }
    float* outp = dir ? gx_b : gx_f;
    outp[tb * 96 + g] = acc;
}

// ---------------- Kernel B: GRU scan, depth-8 register prefetch -------------
__global__ __launch_bounds__(64) void gru_kernel(
    const float* __restrict__ gx_f, const float* __restrict__ gx_b,
    const float* __restrict__ whh_f, const float* __restrict__ bhh_f,
    const float* __restrict__ whh_b, const float* __restrict__ bhh_b,
    float* __restrict__ hseq) {
    int cid = blockIdx.x;            // 0..255
    int b = cid >> 1;
    int dir = cid & 1;
    int lane = threadIdx.x;          // 0..63
    int i = lane & 31;
    int s = lane >> 5;
    int c0 = s * 16;
    const float* whh = dir ? whh_b : whh_f;
    const float* bhh = dir ? bhh_b : bhh_f;
    const float* gx = dir ? gx_b : gx_f;

    float wr[16], wz[16], wn[16];
#pragma unroll
    for (int jj = 0; jj < 16; ++jj) {
        wr[jj] = whh[(size_t)i * HH + c0 + jj];
        wz[jj] = whh[(size_t)(HH + i) * HH + c0 + jj];
        wn[jj] = whh[(size_t)(2 * HH + i) * HH + c0 + jj];
    }
    float bhr = bhh[i], bhz = bhh[HH + i], bhn = bhh[2 * HH + i];

    float h = 0.f;
    float fxr[8], fxz[8], fxn[8];
#pragma unroll
    for (int u = 0; u < 8; ++u) {
        int rt = dir ? (511 - u) : u;
        const float* rp = gx + ((size_t)rt * B + b) * 96;
        fxr[u] = rp[i]; fxz[u] = rp[HH + i]; fxn[u] = rp[2 * HH + i];
    }

    for (int tq = 0; tq < 128; ++tq) {
#pragma unroll
        for (int u = 0; u < 4; ++u) {
            int tc = tq * 4 + u;
            int rt = dir ? (511 - tc) : tc;
            float hr = 0.f, hz = 0.f, hn = 0.f;
#pragma unroll
            for (int jj = 0; jj < 16; ++jj) {
                float hj = __shfl(h, c0 + jj, 64);
                hr = fmaf(wr[jj], hj, hr);
                hz = fmaf(wz[jj], hj, hz);
                hn = fmaf(wn[jj], hj, hn);
            }
            hr += __shfl_xor(hr, 32, 64);
            hz += __shfl_xor(hz, 32, 64);
            hn += __shfl_xor(hn, 32, 64);
            float rg = 1.f / (1.f + __expf(-(fxr[u] + hr + bhr)));
            float zg = 1.f / (1.f + __expf(-(fxz[u] + hz + bhz)));
            float narg = fxn[u] + rg * (hn + bhn);
            float e2 = __expf(-2.f * fabsf(narg));
            float n = copysignf((1.f - e2) / (1.f + e2), narg);
            h = (1.f - zg) * n + zg * h;
            if (s == 0) {
                hseq[((size_t)rt * B + b) * 64 + dir * HH + i] = h;
            }
        }
#pragma unroll
        for (int u = 0; u < 4; ++u) { fxr[u] = fxr[u + 4]; fxz[u] = fxz[u + 4]; fxn[u] = fxn[u + 4]; }
#pragma unroll
        for (int u = 0; u < 4; ++u) {
            int sc = tq * 4 + 8 + u; if (sc > 511) sc = 511;
            int rt = dir ? (511 - sc) : sc;
            const float* rp = gx + ((size_t)rt * B + b) * 96;
            fxr[4 + u] = rp[i]; fxz[4 + u] = rp[HH + i]; fxn[4 + u] = rp[2 * HH + i];
        }
    }
}

// ---------------- Kernel C: logits' = (h_seq @ wl^T + bl) * (1/tau) ---------
__global__ __launch_bounds__(256) void logits_kernel(
    const float* __restrict__ hseq,
    const float* __restrict__ wl, const float* __restrict__ bl,
    const float* __restrict__ wi, const float* __restrict__ bi,
    float* __restrict__ logits, float* __restrict__ initl) {
    int q = threadIdx.x >> 6;
    int tb = blockIdx.x * 4 + q;   // t*B + b
    int g = threadIdx.x & 63;
    __shared__ float hrow[4][64];
    hrow[q][g] = hseq[(size_t)tb * 64 + g];
    __syncthreads();
    float acc = bl[g];
    const float* wrow = wl + (size_t)g * 64;
#pragma unroll
    for (int c = 0; c < 64; ++c) acc = fmaf(wrow[c], hrow[q][c], acc);
    logits[(size_t)tb * 64 + g] = acc * TINV;
    if (tb < B && g < 8) {            // t == 0 blocks, tb == b
        float a2 = bi[g];
        const float* w2 = wi + (size_t)g * 64;
#pragma unroll
        for (int c = 0; c < 64; ++c) a2 = fmaf(w2[c], hrow[q][c], a2);
        initl[tb * 8 + g] = a2;
    }
}

// ---------------- Kernel G: gumbel noise [t][b][8], pre-scaled by 1/tau -----
__global__ __launch_bounds__(256) void gsc_kernel(
    const float* __restrict__ u0, const float* __restrict__ useq,
    float* __restrict__ gs) {
    int id = blockIdx.x * 256 + threadIdx.x;
    if (id >= T * B * KK) return;
    int j = id & 7;
    int b = (id >> 3) & 127;
    int t = id >> 10;
    float u = (t == 0) ? u0[b * 8 + j]
                       : useq[((size_t)b * (T - 1) + (t - 1)) * 8 + j];
    gs[id] = -logf(-logf(u)) * TINV;   // precise logf: u near 1 is ill-conditioned
}

// ---------------- Kernel D: y-only scan, asm-DMA LDS pipeline depth 6 -------
// 4 blocks x 64 lanes; lanes 0..31 each own one batch chain (b = blk*32+r).
// Per iter: 9 DMA (8 logits + 1 gs) + 2 asm y-stores = 11 vm ops -> vmcnt(46)
// keeps 5 slots in flight; LDS XOR-swizzled (read col = m ^ (row&7)), DMA
// source pre-swizzled to match (linear LDS write order).
__global__ __launch_bounds__(64, 1) void scan_kernel(
    const float* __restrict__ logits, const float* __restrict__ initl,
    const float* __restrict__ gs, float* __restrict__ yseq) {
    __shared__ float lds[6][2304];   // 6 slots x (32*64 logits + 32*8 gs) = 55296 B
    int r = threadIdx.x;             // 0..63 (DMA helper); 0..31 active compute
    int b0 = blockIdx.x * 32;
    int b = b0 + (r & 31);
    int r7 = r & 7;

    unsigned ldsU = (unsigned)(unsigned long long)(as3f*)(&lds[0][0]);

    // per-lane pre-swizzled DMA byte offsets (loop-invariant)
    int lof[8];
#pragma unroll
    for (int q = 0; q < 8; ++q) {
        int rr = q * 4 + (r >> 4);         // 0..31 tile row
        int cc = r & 15;                   // linear float4 col
        lof[q] = (((b0 + rr) * 64) + ((cc ^ (rr & 7)) << 2)) << 2;
    }
    int gof;
    {
        int rg = r >> 1;                   // 0..31
        int cc = r & 1;
        gof = (((b0 + rg) * 8) + ((cc ^ (rg & 1)) << 2)) << 2;
    }

#define ISSUE(tt, sl) do {                                                   \
        unsigned lb_ = ldsU + (unsigned)((sl) * 9216);                       \
        const char* bt_ = (const char*)logits + (size_t)(tt) * 32768;        \
        const char* gt_ = (const char*)gs + (size_t)(tt) * 4096;             \
        dma16(lb_ + 0 * 1024u, lof[0], bt_);                                 \
        dma16(lb_ + 1 * 1024u, lof[1], bt_);                                 \
        dma16(lb_ + 2 * 1024u, lof[2], bt_);                                 \
        dma16(lb_ + 3 * 1024u, lof[3], bt_);                                 \
        dma16(lb_ + 4 * 1024u, lof[4], bt_);                                 \
        dma16(lb_ + 5 * 1024u, lof[5], bt_);                                 \
        dma16(lb_ + 6 * 1024u, lof[6], bt_);                                 \
        dma16(lb_ + 7 * 1024u, lof[7], bt_);                                 \
        dma16(lb_ + 8192u, gof, gt_);                                        \
    } while (0)

    f4v* yp = (f4v*)(yseq + (size_t)b * T * 8);
    float y[8];

    // ---- t = 0 from initl + gs[0] (plain loads; completes before DMAs) ----
    if (r < 32) {
        const f4v* il4 = (const f4v*)(initl + b * 8);
        f4v i0 = il4[0], i1 = il4[1];
        const f4v* g4 = (const f4v*)(gs + b * 8);
        f4v G0 = g4[0], G1 = g4[1];
        float a[8];
        a[0] = fmaf(i0.x, TINV, G0.x); a[1] = fmaf(i0.y, TINV, G0.y);
        a[2] = fmaf(i0.z, TINV, G0.z); a[3] = fmaf(i0.w, TINV, G0.w);
        a[4] = fmaf(i1.x, TINV, G1.x); a[5] = fmaf(i1.y, TINV, G1.y);
        a[6] = fmaf(i1.z, TINV, G1.z); a[7] = fmaf(i1.w, TINV, G1.w);
        float m = fmaxf(fmaxf(fmaxf(a[0], a[1]), fmaxf(a[2], a[3])),
                        fmaxf(fmaxf(a[4], a[5]), fmaxf(a[6], a[7])));
        float ssum = 0.f;
#pragma unroll
        for (int j = 0; j < 8; ++j) { y[j] = __expf(a[j] - m); ssum += y[j]; }
        float sinv = __builtin_amdgcn_rcpf(ssum);
#pragma unroll
        for (int j = 0; j < 8; ++j) y[j] *= sinv;
    }
    f4v y0v, y1v;
    if (r < 32) {
        y0v = (f4v){y[0], y[1], y[2], y[3]};
        y1v = (f4v){y[4], y[5], y[6], y[7]};
    }

    // ---- prologue: 5 slot-issues, padded with duplicate y0 stores so the
    // in-flight FIFO pattern exactly matches steady state (9+2 per group) ----
#pragma unroll
    for (int p = 1; p <= 5; ++p) {
        ISSUE(p, p);
        if (r < 32) { st16(&yp[0], y0v); st16(&yp[1], y1v); }
    }

    const f4v* R4 = (const f4v*)(&lds[0][0]);

    for (int t = 1; t < T; ++t) {
        asm volatile("s_waitcnt vmcnt(46)" ::: "memory");
        __builtin_amdgcn_sched_barrier(0);
        {
            int tp = t + 5; if (tp > T - 1) tp = T - 1;
            ISSUE(tp, (t + 5) % 6);
        }
        int sl = t % 6;
        const f4v* S4 = R4 + sl * 576;
        if (r < 32) {
            f4v ga = S4[512 + (r & 31) * 2 + (r & 1)];
            f4v gb = S4[512 + (r & 31) * 2 + ((r & 1) ^ 1)];
            float a[8] = {ga.x, ga.y, ga.z, ga.w, gb.x, gb.y, gb.z, gb.w};
            const f4v* row = S4 + (r & 31) * 16;
#pragma unroll
            for (int k = 0; k < 8; ++k) {
                f4v w0 = row[(2 * k) ^ r7];
                f4v w1 = row[(2 * k + 1) ^ r7];
                float yk = y[k];
                a[0] = fmaf(yk, w0.x, a[0]); a[1] = fmaf(yk, w0.y, a[1]);
                a[2] = fmaf(yk, w0.z, a[2]); a[3] = fmaf(yk, w0.w, a[3]);
                a[4] = fmaf(yk, w1.x, a[4]); a[5] = fmaf(yk, w1.y, a[5]);
                a[6] = fmaf(yk, w1.z, a[6]); a[7] = fmaf(yk, w1.w, a[7]);
            }
            float m = fmaxf(fmaxf(fmaxf(a[0], a[1]), fmaxf(a[2], a[3])),
                            fmaxf(fmaxf(a[4], a[5]), fmaxf(a[6], a[7])));
            float ssum = 0.f;
#pragma unroll
            for (int j = 0; j < 8; ++j) { y[j] = __expf(a[j] - m); ssum += y[j]; }
            float sinv = __builtin_amdgcn_rcpf(ssum);
#pragma unroll
            for (int j = 0; j < 8; ++j) y[j] *= sinv;
            f4v v0 = (f4v){y[0], y[1], y[2], y[3]};
            f4v v1 = (f4v){y[4], y[5], y[6], y[7]};
            st16(&yp[2 * t], v0);
            st16(&yp[2 * t + 1], v1);
        }
    }
#undef ISSUE
}

// ---------------- Kernel E: parallel log_q / log_p --------------------------
__global__ __launch_bounds__(256) void lqlp_kernel(
    const float* __restrict__ logits, const float* __restrict__ initl,
    const float* __restrict__ yseq,
    float* __restrict__ logq, float* __restrict__ logp) {
    int tid = blockIdx.x * 256 + threadIdx.x;   // tid = b*T + t
    if (tid >= B * T) return;
    int b = tid >> 9;
    int t = tid & (T - 1);

    const float4* yt4 = (const float4*)(yseq + (size_t)tid * 8);
    float4 y0 = yt4[0], y1 = yt4[1];
    float yt[8] = {y0.x, y0.y, y0.z, y0.w, y1.x, y1.y, y1.z, y1.w};

    float l[8];
    float lp;
    if (t == 0) {
        const float4* il4 = (const float4*)(initl + b * 8);
        float4 i0 = il4[0], i1 = il4[1];
        l[0] = i0.x; l[1] = i0.y; l[2] = i0.z; l[3] = i0.w;
        l[4] = i1.x; l[5] = i1.y; l[6] = i1.z; l[7] = i1.w;
        float sy = ((yt[0] + yt[1]) + (yt[2] + yt[3])) + ((yt[4] + yt[5]) + (yt[6] + yt[7]));
        lp = LOG_INV_K * sy;
    } else {
        const float4* yp4 = (const float4*)(yseq + (size_t)tid * 8 - 8);
        float4 p0 = yp4[0], p1 = yp4[1];
        float ypv[8] = {p0.x, p0.y, p0.z, p0.w, p1.x, p1.y, p1.z, p1.w};
        const float4* L4 = (const float4*)(logits + ((size_t)t * B + b) * 64);
#pragma unroll
        for (int j = 0; j < 8; ++j) l[j] = 0.f;
#pragma unroll
        for (int k = 0; k < 8; ++k) {
            float4 w0 = L4[2 * k], w1 = L4[2 * k + 1];
            float yk = ypv[k];
            l[0] = fmaf(yk, w0.x, l[0]); l[1] = fmaf(yk, w0.y, l[1]);
            l[2] = fmaf(yk, w0.z, l[2]); l[3] = fmaf(yk, w0.w, l[3]);
            l[4] = fmaf(yk, w1.x, l[4]); l[5] = fmaf(yk, w1.y, l[5]);
            l[6] = fmaf(yk, w1.z, l[6]); l[7] = fmaf(yk, w1.w, l[7]);
        }
#pragma unroll
        for (int j = 0; j < 8; ++j) l[j] *= 0.5f;   // stored logits are pre-scaled by 1/tau
        float sy = ((ypv[0] + ypv[1]) + (ypv[2] + ypv[3])) + ((ypv[4] + ypv[5]) + (ypv[6] + ypv[7]));
        float acc = 0.f;
#pragma unroll
        for (int j = 0; j < 8; ++j) {
            float tp = fmaf(DPS, ypv[j], OFFV * sy);
            acc = fmaf(yt[j], logf(fmaxf(tp, 1e-8f)), acc);
        }
        lp = acc;
    }
    float m = fmaxf(fmaxf(fmaxf(l[0], l[1]), fmaxf(l[2], l[3])),
                    fmaxf(fmaxf(l[4], l[5]), fmaxf(l[6], l[7])));
    float se = 0.f;
#pragma unroll
    for (int j = 0; j < 8; ++j) se += __expf(l[j] - m);
    float lse = m + logf(se);
    float lq = 0.f;
#pragma unroll
    for (int j = 0; j < 8; ++j) lq = fmaf(yt[j], l[j] - lse, lq);
    logq[tid] = lq;
    logp[tid] = lp;
}

// ---------------- Kernel F: output einsums + C broadcast (float4 stores) ----
__global__ __launch_bounds__(128) void out_kernel(
    const float* __restrict__ yseq,
    const float* __restrict__ A, const float* __restrict__ Bm,
    const float* __restrict__ C, const float* __restrict__ Q,
    float4* __restrict__ out4) {
    int bt = blockIdx.x;   // b*T + t
    __shared__ float ys[8];
    if (threadIdx.x < 8) ys[threadIdx.x] = yseq[(size_t)bt * 8 + threadIdx.x];
    __syncthreads();
    float yr[8];
#pragma unroll
    for (int k = 0; k < 8; ++k) yr[k] = ys[k];

    const float4* A4 = (const float4*)A;
    const float4* B4 = (const float4*)Bm;
    const float4* Q4 = (const float4*)Q;
    const float4* C4 = (const float4*)C;

    for (int q = threadIdx.x; q < 288; q += 128) {
        float4 v = make_float4(0.f, 0.f, 0.f, 0.f);
        size_t oidx;
        if (q < 64) {
#pragma unroll
            for (int k = 0; k < 8; ++k) {
                float4 w = A4[k * 64 + q];
                v.x = fmaf(yr[k], w.x, v.x);
                v.y = fmaf(yr[k], w.y, v.y);
                v.z = fmaf(yr[k], w.z, v.z);
                v.w = fmaf(yr[k], w.w, v.w);
            }
            oidx = (size_t)(OUT_A / 4) + (size_t)bt * 64 + q;
        } else if (q < 96) {
            int qb = q - 64;
#pragma unroll
            for (int k = 0; k < 8; ++k) {
                float4 w = B4[k * 32 + qb];
                v.x = fmaf(yr[k], w.x, v.x);
                v.y = fmaf(yr[k], w.y, v.y);
                v.z = fmaf(yr[k], w.z, v.z);
                v.w = fmaf(yr[k], w.w, v.w);
            }
            oidx = (size_t)(OUT_B / 4) + (size_t)bt * 32 + qb;
        } else if (q < 160) {
            int qq = q - 96;
#pragma unroll
            for (int k = 0; k < 8; ++k) {
                float4 w = Q4[k * 64 + qq];
                v.x = fmaf(yr[k], w.x, v.x);
                v.y = fmaf(yr[k], w.y, v.y);
                v.z = fmaf(yr[k], w.z, v.z);
                v.w = fmaf(yr[k], w.w, v.w);
            }
            oidx = (size_t)(OUT_Q / 4) + (size_t)bt * 64 + qq;
        } else {
            int qc = q - 160;
            v = C4[qc];
            oidx = (size_t)(OUT_C / 4) + (size_t)bt * 128 + qc;
        }
        out4[oidx] = v;
    }
}

extern "C" void kernel_launch(void* const* d_in, const int* in_sizes, int n_in,
                              void* d_out, int out_size, void* d_ws, size_t ws_size,
                              hipStream_t stream) {
    const float* a_seq = (const float*)d_in[0];
    const float* A     = (const float*)d_in[1];
    const float* Bmat  = (const float*)d_in[2];
    const float* C     = (const float*)d_in[3];
    const float* Q     = (const float*)d_in[4];
    const float* wih_f = (const float*)d_in[5];
    const float* whh_f = (const float*)d_in[6];
    const float* bih_f = (const float*)d_in[7];
    const float* bhh_f = (const float*)d_in[8];
    const float* wih_b = (const float*)d_in[9];
    const float* whh_b = (const float*)d_in[10];
    const float* bih_b = (const float*)d_in[11];
    const float* bhh_b = (const float*)d_in[12];
    const float* wl    = (const float*)d_in[13];
    const float* bl    = (const float*)d_in[14];
    const float* wi    = (const float*)d_in[15];
    const float* bi    = (const float*)d_in[16];
    const float* u0    = (const float*)d_in[17];
    const float* useq  = (const float*)d_in[18];

    float* ws = (float*)d_ws;
    float* gx_f   = ws + WS_GXF;
    float* gx_b   = ws + WS_GXB;
    float* gsb    = ws + WS_GS;       // aliases gx_b (written after GRU)
    float* hseq   = ws + WS_HSEQ;
    float* logits = ws + WS_LOGITS;   // aliases gx_f (written after GRU)
    float* initl  = ws + WS_INIT;
    float* yseq   = ws + WS_YSEQ;

    float* outf = (float*)d_out;
    float* logq = outf + OUT_LQ;
    float* logp = outf + OUT_LP;

    {
        size_t total = (size_t)T * B * 192;
        int blk = 256;
        int grid = (int)((total + blk - 1) / blk);
        gx_kernel<<<grid, blk, 0, stream>>>(a_seq, wih_f, bih_f, wih_b, bih_b, gx_f, gx_b);
    }
    gru_kernel<<<256, 64, 0, stream>>>(gx_f, gx_b, whh_f, bhh_f, whh_b, bhh_b, hseq);
    {
        int total = B * T * KK;
        gsc_kernel<<<(total + 255) / 256, 256, 0, stream>>>(u0, useq, gsb);
    }
    logits_kernel<<<T * B / 4, 256, 0, stream>>>(hseq, wl, bl, wi, bi, logits, initl);
    scan_kernel<<<4, 64, 0, stream>>>(logits, initl, gsb, yseq);
    lqlp_kernel<<<(B * T + 255) / 256, 256, 0, stream>>>(logits, initl, yseq, logq, logp);
    out_kernel<<<B * T, 128, 0, stream>>>(yseq, A, Bmat, C, Q, (float4*)d_out);
}

// Round 4
// 839.981 us; speedup vs baseline: 1.4180x; 1.1543x over previous
//
#include <hip/hip_runtime.h>
#include <math.h>

#define T 512
#define B 128
#define KK 8
#define HH 32
#define PP 32

// ws layout (floats)
#define WS_GX    0             /* gx [dir*B+b][t][96] = 12582912 floats */
#define WS_GS    6291456       /* alias gx dir=1 half: gumbel noise [t][b][8], written after GRU */
#define WS_HSEQ  12582912
#define WS_LOGITS 0            /* alias gx dir=0 half: scaled logits [t][b][64], written after GRU */
#define WS_INIT  16777216
#define WS_YSEQ  16778240

// d_out layout (floats)
#define OUT_A    0
#define OUT_B    16777216
#define OUT_C    25165824
#define OUT_Q    58720256
#define OUT_LQ   75497472
#define OUT_LP   75563008

#define TINV 2.0f
#define PSTAY 0.9f
#define OFFV (0.1f / 7.0f)
#define DPS (PSTAY - OFFV)
#define LOG_INV_K (-2.0794415416798357f)

typedef float f4v __attribute__((ext_vector_type(4)));
typedef __attribute__((address_space(3))) float as3f;

// async DMA global->LDS, 16B/lane, opaque to compiler (no auto waitcnt insertion)
__device__ __forceinline__ void dma16(unsigned ldsbyte, int voffbyte, const void* sbase) {
    asm volatile("s_mov_b32 m0, %0\n\t"
                 "global_load_lds_dwordx4 %1, %2"
                 :: "s"(ldsbyte), "v"(voffbyte), "s"(sbase)
                 : "memory");
}
// stores kept in asm: compiler does not track them -> no per-iter vmcnt drains
__device__ __forceinline__ void st16(void* p, f4v v) {
    asm volatile("global_store_dwordx4 %0, %1, off" :: "v"(p), "v"(v) : "memory");
}

// ---------------- Kernel A: gx = x @ wih^T + bih, layout [dir*B+b][t][96] ---
__global__ __launch_bounds__(256) void gx_kernel(
    const float* __restrict__ a_seq,
    const float* __restrict__ wih_f, const float* __restrict__ bih_f,
    const float* __restrict__ wih_b, const float* __restrict__ bih_b,
    float* __restrict__ gx) {
    size_t idx = (size_t)blockIdx.x * blockDim.x + threadIdx.x;
    size_t total = (size_t)T * B * 192;
    if (idx >= total) return;
    int g192 = (int)(idx % 192);
    size_t tb = idx / 192;          // t*B + b
    int b = (int)(tb % B);
    int t = (int)(tb / B);
    int dir = g192 / 96;
    int g = g192 % 96;
    const float* w = dir ? wih_b : wih_f;
    const float* bb = dir ? bih_b : bih_f;
    const float4* x4 = (const float4*)(a_seq + ((size_t)b * T + t) * PP);
    const float4* w4 = (const float4*)(w + (size_t)g * PP);
    float acc = bb[g];
#pragma unroll
    for (int q = 0; q < 8; ++q) {
        float4 xv = x4[q];
        float4 wv = w4[q];
        acc = fmaf(xv.x, wv.x, acc);
        acc = fmaf(xv.y, wv.y, acc);
        acc = fmaf(xv.z, wv.z, acc);
        acc = fmaf(xv.w, wv.w, acc);
    }
    gx[((size_t)(dir * B + b) * T + t) * 96 + g] = acc;
}

// ---------------- Kernel B: GRU scan, readlane-broadcast, no LDS ------------
// 1 wave per (dir,b) chain. Lane l computes h[l&31] (halves duplicated).
// h broadcast via v_readlane -> 32 SGPRs; 96 fma/lane/step; asm store.
__global__ __launch_bounds__(64) void gru_kernel(
    const float* __restrict__ gx,
    const float* __restrict__ whh_f, const float* __restrict__ bhh_f,
    const float* __restrict__ whh_b, const float* __restrict__ bhh_b,
    float* __restrict__ hseq) {
    int cid = blockIdx.x;            // 0..255 = dir*128 + b
    int b = cid & 127;
    int dir = cid >> 7;
    int l = threadIdx.x;
    int i = l & 31;
    const float* whh = dir ? whh_b : whh_f;
    const float* bhh = dir ? bhh_b : bhh_f;
    const float* gp0 = gx + (size_t)cid * (T * 96);

    float wr[32], wz[32], wn[32];
#pragma unroll
    for (int q = 0; q < 8; ++q) {
        float4 a0 = *(const float4*)(whh + (size_t)i * 32 + q * 4);
        float4 a1 = *(const float4*)(whh + (size_t)(32 + i) * 32 + q * 4);
        float4 a2 = *(const float4*)(whh + (size_t)(64 + i) * 32 + q * 4);
        wr[q * 4 + 0] = a0.x; wr[q * 4 + 1] = a0.y; wr[q * 4 + 2] = a0.z; wr[q * 4 + 3] = a0.w;
        wz[q * 4 + 0] = a1.x; wz[q * 4 + 1] = a1.y; wz[q * 4 + 2] = a1.z; wz[q * 4 + 3] = a1.w;
        wn[q * 4 + 0] = a2.x; wn[q * 4 + 1] = a2.y; wn[q * 4 + 2] = a2.z; wn[q * 4 + 3] = a2.w;
    }
    float bhr = bhh[i], bhz = bhh[32 + i], bhn = bhh[64 + i];

    const float* p = gp0 + (dir ? (T - 1) * 96 : 0);
    int gstep = dir ? -96 : 96;
    int voff = (((dir ? (T - 1) : 0) * B + b) * 64 + dir * 32 + i) * 4;
    int vstep = dir ? -(B * 64 * 4) : (B * 64 * 4);

    float pxr[8], pxz[8], pxn[8];
#pragma unroll
    for (int s = 0; s < 8; ++s) {
        const float* rp = p + s * gstep;
        pxr[s] = rp[i]; pxz[s] = rp[32 + i]; pxn[s] = rp[64 + i];
    }
    float h = 0.f;

#define GSTEP(SLOT) do {                                                       \
        float hr_ = pxr[SLOT] + bhr;                                           \
        float hz_ = pxz[SLOT] + bhz;                                           \
        float hn_ = bhn;                                                       \
        _Pragma("unroll")                                                      \
        for (int jj = 0; jj < 32; ++jj) {                                      \
            float hj_ = __uint_as_float(                                       \
                __builtin_amdgcn_readlane(__float_as_uint(h), jj));            \
            hr_ = fmaf(wr[jj], hj_, hr_);                                      \
            hz_ = fmaf(wz[jj], hj_, hz_);                                      \
            hn_ = fmaf(wn[jj], hj_, hn_);                                      \
        }                                                                      \
        float r_ = __builtin_amdgcn_rcpf(1.f + __expf(-hr_));                  \
        float z_ = __builtin_amdgcn_rcpf(1.f + __expf(-hz_));                  \
        float na_ = fmaf(r_, hn_, pxn[SLOT]);                                  \
        float e2_ = __expf(-2.f * fabsf(na_));                                 \
        float n_ = copysignf((1.f - e2_) * __builtin_amdgcn_rcpf(1.f + e2_), na_); \
        h = fmaf(z_, h - n_, n_);                                              \
        asm volatile("global_store_dword %0, %1, %2"                           \
                     :: "v"(voff), "v"(h), "s"(hseq) : "memory");              \
        voff += vstep;                                                         \
    } while (0)

    for (int tq = 0; tq < 64; ++tq) {
        GSTEP(0); GSTEP(1); GSTEP(2); GSTEP(3);
#pragma unroll
        for (int u = 0; u < 4; ++u) {
            int sc = tq * 8 + 8 + u; if (sc > T - 1) sc = T - 1;
            const float* rp = p + sc * gstep;
            pxr[u] = rp[i]; pxz[u] = rp[32 + i]; pxn[u] = rp[64 + i];
        }
        GSTEP(4); GSTEP(5); GSTEP(6); GSTEP(7);
#pragma unroll
        for (int u = 0; u < 4; ++u) {
            int sc = tq * 8 + 12 + u; if (sc > T - 1) sc = T - 1;
            const float* rp = p + sc * gstep;
            pxr[4 + u] = rp[i]; pxz[4 + u] = rp[32 + i]; pxn[4 + u] = rp[64 + i];
        }
    }
#undef GSTEP
}

// ---------------- Kernel C: logits' = (h_seq @ wl^T + bl) * (1/tau) ---------
__global__ __launch_bounds__(256) void logits_kernel(
    const float* __restrict__ hseq,
    const float* __restrict__ wl, const float* __restrict__ bl,
    const float* __restrict__ wi, const float* __restrict__ bi,
    float* __restrict__ logits, float* __restrict__ initl) {
    int q = threadIdx.x >> 6;
    int tb = blockIdx.x * 4 + q;   // t*B + b
    int g = threadIdx.x & 63;
    __shared__ float hrow[4][64];
    hrow[q][g] = hseq[(size_t)tb * 64 + g];
    __syncthreads();
    float acc = bl[g];
    const float* wrow = wl + (size_t)g * 64;
#pragma unroll
    for (int c = 0; c < 64; ++c) acc = fmaf(wrow[c], hrow[q][c], acc);
    logits[(size_t)tb * 64 + g] = acc * TINV;
    if (tb < B && g < 8) {            // t == 0 blocks, tb == b
        float a2 = bi[g];
        const float* w2 = wi + (size_t)g * 64;
#pragma unroll
        for (int c = 0; c < 64; ++c) a2 = fmaf(w2[c], hrow[q][c], a2);
        initl[tb * 8 + g] = a2;
    }
}

// ---------------- Kernel G: gumbel noise [t][b][8], pre-scaled by 1/tau -----
__global__ __launch_bounds__(256) void gsc_kernel(
    const float* __restrict__ u0, const float* __restrict__ useq,
    float* __restrict__ gs) {
    int id = blockIdx.x * 256 + threadIdx.x;
    if (id >= T * B * KK) return;
    int j = id & 7;
    int b = (id >> 3) & 127;
    int t = id >> 10;
    float u = (t == 0) ? u0[b * 8 + j]
                       : useq[((size_t)b * (T - 1) + (t - 1)) * 8 + j];
    gs[id] = -logf(-logf(u)) * TINV;   // precise logf: u near 1 is ill-conditioned
}

// ---------------- Kernel D: y-only scan, asm-DMA LDS ring + reg prefetch ----
// 4 blocks x 64 lanes; lanes 0..31 own batch chains. Per phase: 9 DMA + 2 asm
// stores = 11 vm ops; slot for step t+1 proven done by vmcnt(35) (4 phases of
// 11 minus its trailing 2 stores... = 2+33). LDS tile reads are register-
// prefetched one step ahead (banked, unroll-2) so only fma+softmax remain on
// the recurrence chain.
__global__ __launch_bounds__(64, 1) void scan_kernel(
    const float* __restrict__ logits, const float* __restrict__ initl,
    const float* __restrict__ gs, float* __restrict__ yseq) {
    __shared__ float lds[6][2304];   // 6 slots x (32*64 logits + 32*8 gs)
    int r = threadIdx.x;
    int b0 = blockIdx.x * 32;
    int b = b0 + (r & 31);
    int r7 = r & 7;

    unsigned ldsU = (unsigned)(unsigned long long)(as3f*)(&lds[0][0]);

    int lof[8];
#pragma unroll
    for (int q = 0; q < 8; ++q) {
        int rr = q * 4 + (r >> 4);
        int cc = r & 15;
        lof[q] = (((b0 + rr) * 64) + ((cc ^ (rr & 7)) << 2)) << 2;
    }
    int gof;
    {
        int rg = r >> 1;
        int cc = r & 1;
        gof = (((b0 + rg) * 8) + ((cc ^ (rg & 1)) << 2)) << 2;
    }

#define ISSUE(tt, sl) do {                                                   \
        unsigned lb_ = ldsU + (unsigned)((sl) * 9216);                       \
        const char* bt_ = (const char*)logits + (size_t)(tt) * 32768;        \
        const char* gt_ = (const char*)gs + (size_t)(tt) * 4096;             \
        dma16(lb_ + 0 * 1024u, lof[0], bt_);                                 \
        dma16(lb_ + 1 * 1024u, lof[1], bt_);                                 \
        dma16(lb_ + 2 * 1024u, lof[2], bt_);                                 \
        dma16(lb_ + 3 * 1024u, lof[3], bt_);                                 \
        dma16(lb_ + 4 * 1024u, lof[4], bt_);                                 \
        dma16(lb_ + 5 * 1024u, lof[5], bt_);                                 \
        dma16(lb_ + 6 * 1024u, lof[6], bt_);                                 \
        dma16(lb_ + 7 * 1024u, lof[7], bt_);                                 \
        dma16(lb_ + 8192u, gof, gt_);                                        \
    } while (0)

#define SREAD(LL, GA, GB, tt) do { if (r < 32) {                             \
        const f4v* S4_ = R4 + ((tt) % 6) * 576;                              \
        _Pragma("unroll")                                                    \
        for (int m_ = 0; m_ < 16; ++m_)                                      \
            LL[m_] = S4_[(r & 31) * 16 + (m_ ^ r7)];                         \
        GA = S4_[512 + (r & 31) * 2 + (r & 1)];                              \
        GB = S4_[512 + (r & 31) * 2 + ((r & 1) ^ 1)];                        \
    } } while (0)

#define SCOMP(LL, GA, GB, tt) do { if (r < 32) {                             \
        float a_[8] = {GA.x, GA.y, GA.z, GA.w, GB.x, GB.y, GB.z, GB.w};      \
        _Pragma("unroll")                                                    \
        for (int k_ = 0; k_ < 8; ++k_) {                                     \
            f4v w0_ = LL[2 * k_], w1_ = LL[2 * k_ + 1];                      \
            float yk_ = y[k_];                                               \
            a_[0] = fmaf(yk_, w0_.x, a_[0]); a_[1] = fmaf(yk_, w0_.y, a_[1]);\
            a_[2] = fmaf(yk_, w0_.z, a_[2]); a_[3] = fmaf(yk_, w0_.w, a_[3]);\
            a_[4] = fmaf(yk_, w1_.x, a_[4]); a_[5] = fmaf(yk_, w1_.y, a_[5]);\
            a_[6] = fmaf(yk_, w1_.z, a_[6]); a_[7] = fmaf(yk_, w1_.w, a_[7]);\
        }                                                                    \
        float m_ = fmaxf(fmaxf(fmaxf(a_[0], a_[1]), fmaxf(a_[2], a_[3])),    \
                         fmaxf(fmaxf(a_[4], a_[5]), fmaxf(a_[6], a_[7])));   \
        float ss_ = 0.f;                                                     \
        _Pragma("unroll")                                                    \
        for (int j_ = 0; j_ < 8; ++j_) { y[j_] = __expf(a_[j_] - m_); ss_ += y[j_]; } \
        float si_ = __builtin_amdgcn_rcpf(ss_);                              \
        _Pragma("unroll")                                                    \
        for (int j_ = 0; j_ < 8; ++j_) y[j_] *= si_;                         \
        f4v v0_ = (f4v){y[0], y[1], y[2], y[3]};                             \
        f4v v1_ = (f4v){y[4], y[5], y[6], y[7]};                             \
        st16(&yp[2 * (tt)], v0_);                                            \
        st16(&yp[2 * (tt) + 1], v1_);                                        \
    } } while (0)

    f4v* yp = (f4v*)(yseq + (size_t)b * T * 8);
    float y[8];

    // ---- t = 0 from initl + gs[0] (plain loads, compiler-tracked) ----
    if (r < 32) {
        const f4v* il4 = (const f4v*)(initl + b * 8);
        f4v i0 = il4[0], i1 = il4[1];
        const f4v* g4 = (const f4v*)(gs + b * 8);
        f4v G0 = g4[0], G1 = g4[1];
        float a[8];
        a[0] = fmaf(i0.x, TINV, G0.x); a[1] = fmaf(i0.y, TINV, G0.y);
        a[2] = fmaf(i0.z, TINV, G0.z); a[3] = fmaf(i0.w, TINV, G0.w);
        a[4] = fmaf(i1.x, TINV, G1.x); a[5] = fmaf(i1.y, TINV, G1.y);
        a[6] = fmaf(i1.z, TINV, G1.z); a[7] = fmaf(i1.w, TINV, G1.w);
        float m = fmaxf(fmaxf(fmaxf(a[0], a[1]), fmaxf(a[2], a[3])),
                        fmaxf(fmaxf(a[4], a[5]), fmaxf(a[6], a[7])));
        float ssum = 0.f;
#pragma unroll
        for (int j = 0; j < 8; ++j) { y[j] = __expf(a[j] - m); ssum += y[j]; }
        float sinv = __builtin_amdgcn_rcpf(ssum);
#pragma unroll
        for (int j = 0; j < 8; ++j) y[j] *= sinv;
    }
    f4v y0v, y1v;
    if (r < 32) {
        y0v = (f4v){y[0], y[1], y[2], y[3]};
        y1v = (f4v){y[4], y[5], y[6], y[7]};
    }

    // ---- prologue: 5 phases (ISSUE + 2 dup y0 stores) = uniform 11-op shape
#pragma unroll
    for (int p = 1; p <= 5; ++p) {
        ISSUE(p, p);
        if (r < 32) { st16(&yp[0], y0v); st16(&yp[1], y1v); }
    }

    const f4v* R4 = (const f4v*)(&lds[0][0]);
    f4v LA[16], LB[16], gaA, gbA, gaB, gbB;

    // slot 1 done when <=46 of the 55 prologue ops outstanding
    asm volatile("s_waitcnt vmcnt(46)" ::: "memory");
    __builtin_amdgcn_sched_barrier(0);
    SREAD(LA, gaA, gbA, 1);

    for (int t = 1; t < T - 1; t += 2) {
        asm volatile("s_waitcnt vmcnt(35)" ::: "memory");
        __builtin_amdgcn_sched_barrier(0);
        { int tp = t + 5; if (tp > T - 1) tp = T - 1; ISSUE(tp, (t + 5) % 6); }
        SREAD(LB, gaB, gbB, t + 1);
        SCOMP(LA, gaA, gbA, t);

        asm volatile("s_waitcnt vmcnt(35)" ::: "memory");
        __builtin_amdgcn_sched_barrier(0);
        { int tp = t + 6; if (tp > T - 1) tp = T - 1; ISSUE(tp, (t + 6) % 6); }
        SREAD(LA, gaA, gbA, t + 2);
        SCOMP(LB, gaB, gbB, t + 1);
    }
    SCOMP(LA, gaA, gbA, T - 1);
#undef ISSUE
#undef SREAD
#undef SCOMP
}

// ---------------- Kernel E: parallel log_q / log_p --------------------------
__global__ __launch_bounds__(256) void lqlp_kernel(
    const float* __restrict__ logits, const float* __restrict__ initl,
    const float* __restrict__ yseq,
    float* __restrict__ logq, float* __restrict__ logp) {
    int tid = blockIdx.x * 256 + threadIdx.x;   // tid = b*T + t
    if (tid >= B * T) return;
    int b = tid >> 9;
    int t = tid & (T - 1);

    const float4* yt4 = (const float4*)(yseq + (size_t)tid * 8);
    float4 y0 = yt4[0], y1 = yt4[1];
    float yt[8] = {y0.x, y0.y, y0.z, y0.w, y1.x, y1.y, y1.z, y1.w};

    float l[8];
    float lp;
    if (t == 0) {
        const float4* il4 = (const float4*)(initl + b * 8);
        float4 i0 = il4[0], i1 = il4[1];
        l[0] = i0.x; l[1] = i0.y; l[2] = i0.z; l[3] = i0.w;
        l[4] = i1.x; l[5] = i1.y; l[6] = i1.z; l[7] = i1.w;
        float sy = ((yt[0] + yt[1]) + (yt[2] + yt[3])) + ((yt[4] + yt[5]) + (yt[6] + yt[7]));
        lp = LOG_INV_K * sy;
    } else {
        const float4* yp4 = (const float4*)(yseq + (size_t)tid * 8 - 8);
        float4 p0 = yp4[0], p1 = yp4[1];
        float ypv[8] = {p0.x, p0.y, p0.z, p0.w, p1.x, p1.y, p1.z, p1.w};
        const float4* L4 = (const float4*)(logits + ((size_t)t * B + b) * 64);
#pragma unroll
        for (int j = 0; j < 8; ++j) l[j] = 0.f;
#pragma unroll
        for (int k = 0; k < 8; ++k) {
            float4 w0 = L4[2 * k], w1 = L4[2 * k + 1];
            float yk = ypv[k];
            l[0] = fmaf(yk, w0.x, l[0]); l[1] = fmaf(yk, w0.y, l[1]);
            l[2] = fmaf(yk, w0.z, l[2]); l[3] = fmaf(yk, w0.w, l[3]);
            l[4] = fmaf(yk, w1.x, l[4]); l[5] = fmaf(yk, w1.y, l[5]);
            l[6] = fmaf(yk, w1.z, l[6]); l[7] = fmaf(yk, w1.w, l[7]);
        }
#pragma unroll
        for (int j = 0; j < 8; ++j) l[j] *= 0.5f;   // stored logits are pre-scaled by 1/tau
        float sy = ((ypv[0] + ypv[1]) + (ypv[2] + ypv[3])) + ((ypv[4] + ypv[5]) + (ypv[6] + ypv[7]));
        float acc = 0.f;
#pragma unroll
        for (int j = 0; j < 8; ++j) {
            float tp = fmaf(DPS, ypv[j], OFFV * sy);
            acc = fmaf(yt[j], logf(fmaxf(tp, 1e-8f)), acc);
        }
        lp = acc;
    }
    float m = fmaxf(fmaxf(fmaxf(l[0], l[1]), fmaxf(l[2], l[3])),
                    fmaxf(fmaxf(l[4], l[5]), fmaxf(l[6], l[7])));
    float se = 0.f;
#pragma unroll
    for (int j = 0; j < 8; ++j) se += __expf(l[j] - m);
    float lse = m + logf(se);
    float lq = 0.f;
#pragma unroll
    for (int j = 0; j < 8; ++j) lq = fmaf(yt[j], l[j] - lse, lq);
    logq[tid] = lq;
    logp[tid] = lp;
}

// ---------------- Kernel F: output einsums + C broadcast (float4 stores) ----
__global__ __launch_bounds__(128) void out_kernel(
    const float* __restrict__ yseq,
    const float* __restrict__ A, const float* __restrict__ Bm,
    const float* __restrict__ C, const float* __restrict__ Q,
    float4* __restrict__ out4) {
    int bt = blockIdx.x;   // b*T + t
    __shared__ float ys[8];
    if (threadIdx.x < 8) ys[threadIdx.x] = yseq[(size_t)bt * 8 + threadIdx.x];
    __syncthreads();
    float yr[8];
#pragma unroll
    for (int k = 0; k < 8; ++k) yr[k] = ys[k];

    const float4* A4 = (const float4*)A;
    const float4* B4 = (const float4*)Bm;
    const float4* Q4 = (const float4*)Q;
    const float4* C4 = (const float4*)C;

    for (int q = threadIdx.x; q < 288; q += 128) {
        float4 v = make_float4(0.f, 0.f, 0.f, 0.f);
        size_t oidx;
        if (q < 64) {
#pragma unroll
            for (int k = 0; k < 8; ++k) {
                float4 w = A4[k * 64 + q];
                v.x = fmaf(yr[k], w.x, v.x);
                v.y = fmaf(yr[k], w.y, v.y);
                v.z = fmaf(yr[k], w.z, v.z);
                v.w = fmaf(yr[k], w.w, v.w);
            }
            oidx = (size_t)(OUT_A / 4) + (size_t)bt * 64 + q;
        } else if (q < 96) {
            int qb = q - 64;
#pragma unroll
            for (int k = 0; k < 8; ++k) {
                float4 w = B4[k * 32 + qb];
                v.x = fmaf(yr[k], w.x, v.x);
                v.y = fmaf(yr[k], w.y, v.y);
                v.z = fmaf(yr[k], w.z, v.z);
                v.w = fmaf(yr[k], w.w, v.w);
            }
            oidx = (size_t)(OUT_B / 4) + (size_t)bt * 32 + qb;
        } else if (q < 160) {
            int qq = q - 96;
#pragma unroll
            for (int k = 0; k < 8; ++k) {
                float4 w = Q4[k * 64 + qq];
                v.x = fmaf(yr[k], w.x, v.x);
                v.y = fmaf(yr[k], w.y, v.y);
                v.z = fmaf(yr[k], w.z, v.z);
                v.w = fmaf(yr[k], w.w, v.w);
            }
            oidx = (size_t)(OUT_Q / 4) + (size_t)bt * 64 + qq;
        } else {
            int qc = q - 160;
            v = C4[qc];
            oidx = (size_t)(OUT_C / 4) + (size_t)bt * 128 + qc;
        }
        out4[oidx] = v;
    }
}

extern "C" void kernel_launch(void* const* d_in, const int* in_sizes, int n_in,
                              void* d_out, int out_size, void* d_ws, size_t ws_size,
                              hipStream_t stream) {
    const float* a_seq = (const float*)d_in[0];
    const float* A     = (const float*)d_in[1];
    const float* Bmat  = (const float*)d_in[2];
    const float* C     = (const float*)d_in[3];
    const float* Q     = (const float*)d_in[4];
    const float* wih_f = (const float*)d_in[5];
    const float* whh_f = (const float*)d_in[6];
    const float* bih_f = (const float*)d_in[7];
    const float* bhh_f = (const float*)d_in[8];
    const float* wih_b = (const float*)d_in[9];
    const float* whh_b = (const float*)d_in[10];
    const float* bih_b = (const float*)d_in[11];
    const float* bhh_b = (const float*)d_in[12];
    const float* wl    = (const float*)d_in[13];
    const float* bl    = (const float*)d_in[14];
    const float* wi    = (const float*)d_in[15];
    const float* bi    = (const float*)d_in[16];
    const float* u0    = (const float*)d_in[17];
    const float* useq  = (const float*)d_in[18];

    float* ws = (float*)d_ws;
    float* gx     = ws + WS_GX;
    float* gsb    = ws + WS_GS;       // aliases gx dir=1 half (written after GRU)
    float* hseq   = ws + WS_HSEQ;
    float* logits = ws + WS_LOGITS;   // aliases gx dir=0 half (written after GRU)
    float* initl  = ws + WS_INIT;
    float* yseq   = ws + WS_YSEQ;

    float* outf = (float*)d_out;
    float* logq = outf + OUT_LQ;
    float* logp = outf + OUT_LP;

    {
        size_t total = (size_t)T * B * 192;
        int blk = 256;
        int grid = (int)((total + blk - 1) / blk);
        gx_kernel<<<grid, blk, 0, stream>>>(a_seq, wih_f, bih_f, wih_b, bih_b, gx);
    }
    gru_kernel<<<256, 64, 0, stream>>>(gx, whh_f, bhh_f, whh_b, bhh_b, hseq);
    {
        int total = B * T * KK;
        gsc_kernel<<<(total + 255) / 256, 256, 0, stream>>>(u0, useq, gsb);
    }
    logits_kernel<<<T * B / 4, 256, 0, stream>>>(hseq, wl, bl, wi, bi, logits, initl);
    scan_kernel<<<4, 64, 0, stream>>>(logits, initl, gsb, yseq);
    lqlp_kernel<<<(B * T + 255) / 256, 256, 0, stream>>>(logits, initl, yseq, logq, logp);
    out_kernel<<<B * T, 128, 0, stream>>>(yseq, A, Bmat, C, Q, (float4*)d_out);
}

// Round 5
// 809.225 us; speedup vs baseline: 1.4719x; 1.0380x over previous
//
#include <hip/hip_runtime.h>
#include <math.h>

#define T 512
#define B 128
#define KK 8
#define HH 32
#define PP 32

// ws layout (floats)
#define WS_GX    0             /* gx [dir*B+b][t][96] = 12582912 floats */
#define WS_GS    6291456       /* alias gx dir=1 half: gumbel noise [t][b][8], written after GRU */
#define WS_HSEQ  12582912
#define WS_LOGITS 0            /* alias gx dir=0 half: scaled logits [t][b][64], written after GRU */
#define WS_INIT  16777216
#define WS_YSEQ  16778240

// d_out layout (floats)
#define OUT_A    0
#define OUT_B    16777216
#define OUT_C    25165824
#define OUT_Q    58720256
#define OUT_LQ   75497472
#define OUT_LP   75563008

#define TINV 2.0f
#define PSTAY 0.9f
#define OFFV (0.1f / 7.0f)
#define DPS (PSTAY - OFFV)
#define LOG_INV_K (-2.0794415416798357f)

typedef float f4v __attribute__((ext_vector_type(4)));
typedef __attribute__((address_space(3))) float as3f;

// async DMA global->LDS, 16B/lane, opaque to compiler (no auto waitcnt insertion)
__device__ __forceinline__ void dma16(unsigned ldsbyte, int voffbyte, const void* sbase) {
    asm volatile("s_mov_b32 m0, %0\n\t"
                 "global_load_lds_dwordx4 %1, %2"
                 :: "s"(ldsbyte), "v"(voffbyte), "s"(sbase)
                 : "memory");
}
// stores kept in asm: compiler does not track them -> no per-iter vmcnt drains
__device__ __forceinline__ void st16(void* p, f4v v) {
    asm volatile("global_store_dwordx4 %0, %1, off" :: "v"(p), "v"(v) : "memory");
}
// pinned LDS read: output lives in registers, cannot be rematerialized at use
__device__ __forceinline__ f4v ldsr16(int addr) {
    f4v out;
    asm volatile("ds_read_b128 %0, %1" : "=v"(out) : "v"(addr));
    return out;
}

// ---------------- Kernel A: gx = x @ wih^T + bih, layout [dir*B+b][t][96] ---
__global__ __launch_bounds__(256) void gx_kernel(
    const float* __restrict__ a_seq,
    const float* __restrict__ wih_f, const float* __restrict__ bih_f,
    const float* __restrict__ wih_b, const float* __restrict__ bih_b,
    float* __restrict__ gx) {
    size_t idx = (size_t)blockIdx.x * blockDim.x + threadIdx.x;
    size_t total = (size_t)T * B * 192;
    if (idx >= total) return;
    int g192 = (int)(idx % 192);
    size_t tb = idx / 192;          // t*B + b
    int b = (int)(tb % B);
    int t = (int)(tb / B);
    int dir = g192 / 96;
    int g = g192 % 96;
    const float* w = dir ? wih_b : wih_f;
    const float* bb = dir ? bih_b : bih_f;
    const float4* x4 = (const float4*)(a_seq + ((size_t)b * T + t) * PP);
    const float4* w4 = (const float4*)(w + (size_t)g * PP);
    float acc = bb[g];
#pragma unroll
    for (int q = 0; q < 8; ++q) {
        float4 xv = x4[q];
        float4 wv = w4[q];
        acc = fmaf(xv.x, wv.x, acc);
        acc = fmaf(xv.y, wv.y, acc);
        acc = fmaf(xv.z, wv.z, acc);
        acc = fmaf(xv.w, wv.w, acc);
    }
    gx[((size_t)(dir * B + b) * T + t) * 96 + g] = acc;
}

// ---------------- Kernel B: GRU scan, readlane-broadcast, no LDS ------------
__global__ __launch_bounds__(64) void gru_kernel(
    const float* __restrict__ gx,
    const float* __restrict__ whh_f, const float* __restrict__ bhh_f,
    const float* __restrict__ whh_b, const float* __restrict__ bhh_b,
    float* __restrict__ hseq) {
    int cid = blockIdx.x;            // 0..255 = dir*128 + b
    int b = cid & 127;
    int dir = cid >> 7;
    int l = threadIdx.x;
    int i = l & 31;
    const float* whh = dir ? whh_b : whh_f;
    const float* bhh = dir ? bhh_b : bhh_f;
    const float* gp0 = gx + (size_t)cid * (T * 96);

    float wr[32], wz[32], wn[32];
#pragma unroll
    for (int q = 0; q < 8; ++q) {
        float4 a0 = *(const float4*)(whh + (size_t)i * 32 + q * 4);
        float4 a1 = *(const float4*)(whh + (size_t)(32 + i) * 32 + q * 4);
        float4 a2 = *(const float4*)(whh + (size_t)(64 + i) * 32 + q * 4);
        wr[q * 4 + 0] = a0.x; wr[q * 4 + 1] = a0.y; wr[q * 4 + 2] = a0.z; wr[q * 4 + 3] = a0.w;
        wz[q * 4 + 0] = a1.x; wz[q * 4 + 1] = a1.y; wz[q * 4 + 2] = a1.z; wz[q * 4 + 3] = a1.w;
        wn[q * 4 + 0] = a2.x; wn[q * 4 + 1] = a2.y; wn[q * 4 + 2] = a2.z; wn[q * 4 + 3] = a2.w;
    }
    float bhr = bhh[i], bhz = bhh[32 + i], bhn = bhh[64 + i];

    const float* p = gp0 + (dir ? (T - 1) * 96 : 0);
    int gstep = dir ? -96 : 96;
    int voff = (((dir ? (T - 1) : 0) * B + b) * 64 + dir * 32 + i) * 4;
    int vstep = dir ? -(B * 64 * 4) : (B * 64 * 4);

    float pxr[8], pxz[8], pxn[8];
#pragma unroll
    for (int s = 0; s < 8; ++s) {
        const float* rp = p + s * gstep;
        pxr[s] = rp[i]; pxz[s] = rp[32 + i]; pxn[s] = rp[64 + i];
    }
    float h = 0.f;

#define GSTEP(SLOT) do {                                                       \
        float hr_ = pxr[SLOT] + bhr;                                           \
        float hz_ = pxz[SLOT] + bhz;                                           \
        float hn_ = bhn;                                                       \
        _Pragma("unroll")                                                      \
        for (int jj = 0; jj < 32; ++jj) {                                      \
            float hj_ = __uint_as_float(                                       \
                __builtin_amdgcn_readlane(__float_as_uint(h), jj));            \
            hr_ = fmaf(wr[jj], hj_, hr_);                                      \
            hz_ = fmaf(wz[jj], hj_, hz_);                                      \
            hn_ = fmaf(wn[jj], hj_, hn_);                                      \
        }                                                                      \
        float r_ = __builtin_amdgcn_rcpf(1.f + __expf(-hr_));                  \
        float z_ = __builtin_amdgcn_rcpf(1.f + __expf(-hz_));                  \
        float na_ = fmaf(r_, hn_, pxn[SLOT]);                                  \
        float e2_ = __expf(-2.f * fabsf(na_));                                 \
        float n_ = copysignf((1.f - e2_) * __builtin_amdgcn_rcpf(1.f + e2_), na_); \
        h = fmaf(z_, h - n_, n_);                                              \
        asm volatile("global_store_dword %0, %1, %2"                           \
                     :: "v"(voff), "v"(h), "s"(hseq) : "memory");              \
        voff += vstep;                                                         \
    } while (0)

    for (int tq = 0; tq < 64; ++tq) {
        GSTEP(0); GSTEP(1); GSTEP(2); GSTEP(3);
#pragma unroll
        for (int u = 0; u < 4; ++u) {
            int sc = tq * 8 + 8 + u; if (sc > T - 1) sc = T - 1;
            const float* rp = p + sc * gstep;
            pxr[u] = rp[i]; pxz[u] = rp[32 + i]; pxn[u] = rp[64 + i];
        }
        GSTEP(4); GSTEP(5); GSTEP(6); GSTEP(7);
#pragma unroll
        for (int u = 0; u < 4; ++u) {
            int sc = tq * 8 + 12 + u; if (sc > T - 1) sc = T - 1;
            const float* rp = p + sc * gstep;
            pxr[4 + u] = rp[i]; pxz[4 + u] = rp[32 + i]; pxn[4 + u] = rp[64 + i];
        }
    }
#undef GSTEP
}

// ---------------- Kernel C: logits' = (h_seq @ wl^T + bl) * (1/tau) ---------
__global__ __launch_bounds__(256) void logits_kernel(
    const float* __restrict__ hseq,
    const float* __restrict__ wl, const float* __restrict__ bl,
    const float* __restrict__ wi, const float* __restrict__ bi,
    float* __restrict__ logits, float* __restrict__ initl) {
    int q = threadIdx.x >> 6;
    int tb = blockIdx.x * 4 + q;   // t*B + b
    int g = threadIdx.x & 63;
    __shared__ float hrow[4][64];
    hrow[q][g] = hseq[(size_t)tb * 64 + g];
    __syncthreads();
    float acc = bl[g];
    const float* wrow = wl + (size_t)g * 64;
#pragma unroll
    for (int c = 0; c < 64; ++c) acc = fmaf(wrow[c], hrow[q][c], acc);
    logits[(size_t)tb * 64 + g] = acc * TINV;
    if (tb < B && g < 8) {            // t == 0 blocks, tb == b
        float a2 = bi[g];
        const float* w2 = wi + (size_t)g * 64;
#pragma unroll
        for (int c = 0; c < 64; ++c) a2 = fmaf(w2[c], hrow[q][c], a2);
        initl[tb * 8 + g] = a2;
    }
}

// ---------------- Kernel G: gumbel noise [t][b][8], pre-scaled by 1/tau -----
__global__ __launch_bounds__(256) void gsc_kernel(
    const float* __restrict__ u0, const float* __restrict__ useq,
    float* __restrict__ gs) {
    int id = blockIdx.x * 256 + threadIdx.x;
    if (id >= T * B * KK) return;
    int j = id & 7;
    int b = (id >> 3) & 127;
    int t = id >> 10;
    float u = (t == 0) ? u0[b * 8 + j]
                       : useq[((size_t)b * (T - 1) + (t - 1)) * 8 + j];
    gs[id] = -logf(-logf(u)) * TINV;   // precise logf: u near 1 is ill-conditioned
}

// ---------------- Kernel D: y-only scan, asm-DMA ring + asm-pinned reads ----
// 4 blocks x 64 lanes; lanes 0..31 own batch chains (upper half duplicates
// compute, stores guarded). Per phase: 9 DMA + 2 asm stores = 11 vm ops;
// vmcnt(35) at phase top proves the slot read this phase is landed.
// LDS tile reads are inline-asm ds_read_b128 (compiler cannot sink them);
// lgkmcnt(0)+sched_barrier before each consuming SCOMP (rule 18).
__global__ __launch_bounds__(64, 1) void scan_kernel(
    const float* __restrict__ logits, const float* __restrict__ initl,
    const float* __restrict__ gs, float* __restrict__ yseq) {
    __shared__ float lds[6][2304];   // 6 slots x (32*64 logits + 32*8 gs)
    int r = threadIdx.x;
    int b0 = blockIdx.x * 32;
    int b = b0 + (r & 31);
    int k15 = r & 15;

    unsigned ldsU = (unsigned)(unsigned long long)(as3f*)(&lds[0][0]);

    // DMA source offsets, pre-swizzled with the same involution the reads use
    int lof[8];
#pragma unroll
    for (int q = 0; q < 8; ++q) {
        int rr = q * 4 + (r >> 4);         // tile row 0..31
        int cc = r & 15;                   // linear f4v col in LDS
        lof[q] = (((b0 + rr) * 64) + ((cc ^ (rr & 15)) << 2)) << 2;
    }
    int gof;
    {
        int rg = r >> 1;
        int cc = r & 1;
        gof = (((b0 + rg) * 8) + ((cc ^ (rg & 1)) << 2)) << 2;
    }
    unsigned rbase = ldsU + (unsigned)((r & 31) * 256);   // per-lane row base
    unsigned gbase = ldsU + 8192u + (unsigned)((r & 31) * 32);

#define ISSUE(tt, sl) do {                                                   \
        unsigned lb_ = ldsU + (unsigned)((sl) * 9216);                       \
        const char* bt_ = (const char*)logits + (size_t)(tt) * 32768;        \
        const char* gt_ = (const char*)gs + (size_t)(tt) * 4096;             \
        dma16(lb_ + 0 * 1024u, lof[0], bt_);                                 \
        dma16(lb_ + 1 * 1024u, lof[1], bt_);                                 \
        dma16(lb_ + 2 * 1024u, lof[2], bt_);                                 \
        dma16(lb_ + 3 * 1024u, lof[3], bt_);                                 \
        dma16(lb_ + 4 * 1024u, lof[4], bt_);                                 \
        dma16(lb_ + 5 * 1024u, lof[5], bt_);                                 \
        dma16(lb_ + 6 * 1024u, lof[6], bt_);                                 \
        dma16(lb_ + 7 * 1024u, lof[7], bt_);                                 \
        dma16(lb_ + 8192u, gof, gt_);                                        \
    } while (0)

#define SREAD(LL, GA, GB, tt) do {                                           \
        int so_ = ((tt) % 6) * 9216;                                         \
        _Pragma("unroll")                                                    \
        for (int m_ = 0; m_ < 16; ++m_)                                      \
            LL[m_] = ldsr16((int)(rbase + so_ + ((m_ ^ k15) << 4)));         \
        GA = ldsr16((int)(gbase + so_ + ((r & 1) << 4)));                    \
        GB = ldsr16((int)(gbase + so_ + (((r & 1) ^ 1) << 4)));              \
    } while (0)

#define LWAIT() do {                                                         \
        asm volatile("s_waitcnt lgkmcnt(0)" ::: "memory");                   \
        __builtin_amdgcn_sched_barrier(0);                                   \
    } while (0)

#define SCOMP(LL, GA, GB, tt) do {                                           \
        float a_[8] = {GA.x, GA.y, GA.z, GA.w, GB.x, GB.y, GB.z, GB.w};      \
        _Pragma("unroll")                                                    \
        for (int k_ = 0; k_ < 8; ++k_) {                                     \
            f4v w0_ = LL[2 * k_], w1_ = LL[2 * k_ + 1];                      \
            float yk_ = y[k_];                                               \
            a_[0] = fmaf(yk_, w0_.x, a_[0]); a_[1] = fmaf(yk_, w0_.y, a_[1]);\
            a_[2] = fmaf(yk_, w0_.z, a_[2]); a_[3] = fmaf(yk_, w0_.w, a_[3]);\
            a_[4] = fmaf(yk_, w1_.x, a_[4]); a_[5] = fmaf(yk_, w1_.y, a_[5]);\
            a_[6] = fmaf(yk_, w1_.z, a_[6]); a_[7] = fmaf(yk_, w1_.w, a_[7]);\
        }                                                                    \
        float m_ = fmaxf(fmaxf(fmaxf(a_[0], a_[1]), fmaxf(a_[2], a_[3])),    \
                         fmaxf(fmaxf(a_[4], a_[5]), fmaxf(a_[6], a_[7])));   \
        float ss_ = 0.f;                                                     \
        _Pragma("unroll")                                                    \
        for (int j_ = 0; j_ < 8; ++j_) { y[j_] = __expf(a_[j_] - m_); ss_ += y[j_]; } \
        float si_ = __builtin_amdgcn_rcpf(ss_);                              \
        _Pragma("unroll")                                                    \
        for (int j_ = 0; j_ < 8; ++j_) y[j_] *= si_;                         \
        if (r < 32) {                                                        \
            f4v v0_ = (f4v){y[0], y[1], y[2], y[3]};                         \
            f4v v1_ = (f4v){y[4], y[5], y[6], y[7]};                         \
            st16(&yp[2 * (tt)], v0_);                                        \
            st16(&yp[2 * (tt) + 1], v1_);                                    \
        }                                                                    \
    } while (0)

    f4v* yp = (f4v*)(yseq + (size_t)b * T * 8);
    float y[8];

    // ---- t = 0 from initl + gs[0] (plain loads, compiler-tracked) ----
    {
        const f4v* il4 = (const f4v*)(initl + b * 8);
        f4v i0 = il4[0], i1 = il4[1];
        const f4v* g4 = (const f4v*)(gs + b * 8);
        f4v G0 = g4[0], G1 = g4[1];
        float a[8];
        a[0] = fmaf(i0.x, TINV, G0.x); a[1] = fmaf(i0.y, TINV, G0.y);
        a[2] = fmaf(i0.z, TINV, G0.z); a[3] = fmaf(i0.w, TINV, G0.w);
        a[4] = fmaf(i1.x, TINV, G1.x); a[5] = fmaf(i1.y, TINV, G1.y);
        a[6] = fmaf(i1.z, TINV, G1.z); a[7] = fmaf(i1.w, TINV, G1.w);
        float m = fmaxf(fmaxf(fmaxf(a[0], a[1]), fmaxf(a[2], a[3])),
                        fmaxf(fmaxf(a[4], a[5]), fmaxf(a[6], a[7])));
        float ssum = 0.f;
#pragma unroll
        for (int j = 0; j < 8; ++j) { y[j] = __expf(a[j] - m); ssum += y[j]; }
        float sinv = __builtin_amdgcn_rcpf(ssum);
#pragma unroll
        for (int j = 0; j < 8; ++j) y[j] *= sinv;
    }
    f4v y0v = (f4v){y[0], y[1], y[2], y[3]};
    f4v y1v = (f4v){y[4], y[5], y[6], y[7]};

    // ---- prologue: 5 phases (ISSUE + 2 dup y0 stores) = uniform 11-op shape
#pragma unroll
    for (int p = 1; p <= 5; ++p) {
        ISSUE(p, p);
        if (r < 32) { st16(&yp[0], y0v); st16(&yp[1], y1v); }
    }

    f4v LA[16], LB[16], gaA, gbA, gaB, gbB;

    // slot 1 done when <=46 of the 55 prologue ops outstanding
    asm volatile("s_waitcnt vmcnt(46)" ::: "memory");
    __builtin_amdgcn_sched_barrier(0);
    SREAD(LA, gaA, gbA, 1);

    for (int t = 1; t < T - 1; t += 2) {
        asm volatile("s_waitcnt vmcnt(35)" ::: "memory");
        __builtin_amdgcn_sched_barrier(0);
        { int tp = t + 5; if (tp > T - 1) tp = T - 1; ISSUE(tp, (t + 5) % 6); }
        LWAIT();                       // LA (or prev LB) reads complete
        SREAD(LB, gaB, gbB, t + 1);
        SCOMP(LA, gaA, gbA, t);

        asm volatile("s_waitcnt vmcnt(35)" ::: "memory");
        __builtin_amdgcn_sched_barrier(0);
        { int tp = t + 6; if (tp > T - 1) tp = T - 1; ISSUE(tp, (t + 6) % 6); }
        LWAIT();
        SREAD(LA, gaA, gbA, t + 2);
        SCOMP(LB, gaB, gbB, t + 1);
    }
    LWAIT();
    SCOMP(LA, gaA, gbA, T - 1);
#undef ISSUE
#undef SREAD
#undef LWAIT
#undef SCOMP
}

// ---------------- Kernel E: parallel log_q / log_p --------------------------
__global__ __launch_bounds__(256) void lqlp_kernel(
    const float* __restrict__ logits, const float* __restrict__ initl,
    const float* __restrict__ yseq,
    float* __restrict__ logq, float* __restrict__ logp) {
    int tid = blockIdx.x * 256 + threadIdx.x;   // tid = b*T + t
    if (tid >= B * T) return;
    int b = tid >> 9;
    int t = tid & (T - 1);

    const float4* yt4 = (const float4*)(yseq + (size_t)tid * 8);
    float4 y0 = yt4[0], y1 = yt4[1];
    float yt[8] = {y0.x, y0.y, y0.z, y0.w, y1.x, y1.y, y1.z, y1.w};

    float l[8];
    float lp;
    if (t == 0) {
        const float4* il4 = (const float4*)(initl + b * 8);
        float4 i0 = il4[0], i1 = il4[1];
        l[0] = i0.x; l[1] = i0.y; l[2] = i0.z; l[3] = i0.w;
        l[4] = i1.x; l[5] = i1.y; l[6] = i1.z; l[7] = i1.w;
        float sy = ((yt[0] + yt[1]) + (yt[2] + yt[3])) + ((yt[4] + yt[5]) + (yt[6] + yt[7]));
        lp = LOG_INV_K * sy;
    } else {
        const float4* yp4 = (const float4*)(yseq + (size_t)tid * 8 - 8);
        float4 p0 = yp4[0], p1 = yp4[1];
        float ypv[8] = {p0.x, p0.y, p0.z, p0.w, p1.x, p1.y, p1.z, p1.w};
        const float4* L4 = (const float4*)(logits + ((size_t)t * B + b) * 64);
#pragma unroll
        for (int j = 0; j < 8; ++j) l[j] = 0.f;
#pragma unroll
        for (int k = 0; k < 8; ++k) {
            float4 w0 = L4[2 * k], w1 = L4[2 * k + 1];
            float yk = ypv[k];
            l[0] = fmaf(yk, w0.x, l[0]); l[1] = fmaf(yk, w0.y, l[1]);
            l[2] = fmaf(yk, w0.z, l[2]); l[3] = fmaf(yk, w0.w, l[3]);
            l[4] = fmaf(yk, w1.x, l[4]); l[5] = fmaf(yk, w1.y, l[5]);
            l[6] = fmaf(yk, w1.z, l[6]); l[7] = fmaf(yk, w1.w, l[7]);
        }
#pragma unroll
        for (int j = 0; j < 8; ++j) l[j] *= 0.5f;   // stored logits are pre-scaled by 1/tau
        float sy = ((ypv[0] + ypv[1]) + (ypv[2] + ypv[3])) + ((ypv[4] + ypv[5]) + (ypv[6] + ypv[7]));
        float acc = 0.f;
#pragma unroll
        for (int j = 0; j < 8; ++j) {
            float tp = fmaf(DPS, ypv[j], OFFV * sy);
            acc = fmaf(yt[j], logf(fmaxf(tp, 1e-8f)), acc);
        }
        lp = acc;
    }
    float m = fmaxf(fmaxf(fmaxf(l[0], l[1]), fmaxf(l[2], l[3])),
                    fmaxf(fmaxf(l[4], l[5]), fmaxf(l[6], l[7])));
    float se = 0.f;
#pragma unroll
    for (int j = 0; j < 8; ++j) se += __expf(l[j] - m);
    float lse = m + logf(se);
    float lq = 0.f;
#pragma unroll
    for (int j = 0; j < 8; ++j) lq = fmaf(yt[j], l[j] - lse, lq);
    logq[tid] = lq;
    logp[tid] = lp;
}

// ---------------- Kernel F: output einsums + C broadcast (float4 stores) ----
__global__ __launch_bounds__(128) void out_kernel(
    const float* __restrict__ yseq,
    const float* __restrict__ A, const float* __restrict__ Bm,
    const float* __restrict__ C, const float* __restrict__ Q,
    float4* __restrict__ out4) {
    int bt = blockIdx.x;   // b*T + t
    __shared__ float ys[8];
    if (threadIdx.x < 8) ys[threadIdx.x] = yseq[(size_t)bt * 8 + threadIdx.x];
    __syncthreads();
    float yr[8];
#pragma unroll
    for (int k = 0; k < 8; ++k) yr[k] = ys[k];

    const float4* A4 = (const float4*)A;
    const float4* B4 = (const float4*)Bm;
    const float4* Q4 = (const float4*)Q;
    const float4* C4 = (const float4*)C;

    for (int q = threadIdx.x; q < 288; q += 128) {
        float4 v = make_float4(0.f, 0.f, 0.f, 0.f);
        size_t oidx;
        if (q < 64) {
#pragma unroll
            for (int k = 0; k < 8; ++k) {
                float4 w = A4[k * 64 + q];
                v.x = fmaf(yr[k], w.x, v.x);
                v.y = fmaf(yr[k], w.y, v.y);
                v.z = fmaf(yr[k], w.z, v.z);
                v.w = fmaf(yr[k], w.w, v.w);
            }
            oidx = (size_t)(OUT_A / 4) + (size_t)bt * 64 + q;
        } else if (q < 96) {
            int qb = q - 64;
#pragma unroll
            for (int k = 0; k < 8; ++k) {
                float4 w = B4[k * 32 + qb];
                v.x = fmaf(yr[k], w.x, v.x);
                v.y = fmaf(yr[k], w.y, v.y);
                v.z = fmaf(yr[k], w.z, v.z);
                v.w = fmaf(yr[k], w.w, v.w);
            }
            oidx = (size_t)(OUT_B / 4) + (size_t)bt * 32 + qb;
        } else if (q < 160) {
            int qq = q - 96;
#pragma unroll
            for (int k = 0; k < 8; ++k) {
                float4 w = Q4[k * 64 + qq];
                v.x = fmaf(yr[k], w.x, v.x);
                v.y = fmaf(yr[k], w.y, v.y);
                v.z = fmaf(yr[k], w.z, v.z);
                v.w = fmaf(yr[k], w.w, v.w);
            }
            oidx = (size_t)(OUT_Q / 4) + (size_t)bt * 64 + qq;
        } else {
            int qc = q - 160;
            v = C4[qc];
            oidx = (size_t)(OUT_C / 4) + (size_t)bt * 128 + qc;
        }
        out4[oidx] = v;
    }
}

extern "C" void kernel_launch(void* const* d_in, const int* in_sizes, int n_in,
                              void* d_out, int out_size, void* d_ws, size_t ws_size,
                              hipStream_t stream) {
    const float* a_seq = (const float*)d_in[0];
    const float* A     = (const float*)d_in[1];
    const float* Bmat  = (const float*)d_in[2];
    const float* C     = (const float*)d_in[3];
    const float* Q     = (const float*)d_in[4];
    const float* wih_f = (const float*)d_in[5];
    const float* whh_f = (const float*)d_in[6];
    const float* bih_f = (const float*)d_in[7];
    const float* bhh_f = (const float*)d_in[8];
    const float* wih_b = (const float*)d_in[9];
    const float* whh_b = (const float*)d_in[10];
    const float* bih_b = (const float*)d_in[11];
    const float* bhh_b = (const float*)d_in[12];
    const float* wl    = (const float*)d_in[13];
    const float* bl    = (const float*)d_in[14];
    const float* wi    = (const float*)d_in[15];
    const float* bi    = (const float*)d_in[16];
    const float* u0    = (const float*)d_in[17];
    const float* useq  = (const float*)d_in[18];

    float* ws = (float*)d_ws;
    float* gx     = ws + WS_GX;
    float* gsb    = ws + WS_GS;       // aliases gx dir=1 half (written after GRU)
    float* hseq   = ws + WS_HSEQ;
    float* logits = ws + WS_LOGITS;   // aliases gx dir=0 half (written after GRU)
    float* initl  = ws + WS_INIT;
    float* yseq   = ws + WS_YSEQ;

    float* outf = (float*)d_out;
    float* logq = outf + OUT_LQ;
    float* logp = outf + OUT_LP;

    {
        size_t total = (size_t)T * B * 192;
        int blk = 256;
        int grid = (int)((total + blk - 1) / blk);
        gx_kernel<<<grid, blk, 0, stream>>>(a_seq, wih_f, bih_f, wih_b, bih_b, gx);
    }
    gru_kernel<<<256, 64, 0, stream>>>(gx, whh_f, bhh_f, whh_b, bhh_b, hseq);
    {
        int total = B * T * KK;
        gsc_kernel<<<(total + 255) / 256, 256, 0, stream>>>(u0, useq, gsb);
    }
    logits_kernel<<<T * B / 4, 256, 0, stream>>>(hseq, wl, bl, wi, bi, logits, initl);
    scan_kernel<<<4, 64, 0, stream>>>(logits, initl, gsb, yseq);
    lqlp_kernel<<<(B * T + 255) / 256, 256, 0, stream>>>(logits, initl, yseq, logq, logp);
    out_kernel<<<B * T, 128, 0, stream>>>(yseq, A, Bmat, C, Q, (float4*)d_out);
}

// Round 7
// 621.504 us; speedup vs baseline: 1.9165x; 1.3020x over previous
//
#include <hip/hip_runtime.h>
#include <math.h>

#define T 512
#define B 128
#define KK 8
#define HH 32
#define PP 32

// ws layout (floats)
#define WS_GX    0             /* gx [dir*B+b][t][96] = 12582912 floats */
#define WS_GS    6291456       /* alias gx dir=1 half: gumbel noise [t][b][8], written after GRU */
#define WS_HSEQ  12582912
#define WS_LOGITS 0            /* alias gx dir=0 half: scaled logits [t][b][64], written after GRU */
#define WS_INIT  16777216
#define WS_YSEQ  16778240

// d_out layout (floats)
#define OUT_A    0
#define OUT_B    16777216
#define OUT_C    25165824
#define OUT_Q    58720256
#define OUT_LQ   75497472
#define OUT_LP   75563008

#define TINV 2.0f
#define PSTAY 0.9f
#define OFFV (0.1f / 7.0f)
#define DPS (PSTAY - OFFV)
#define LOG_INV_K (-2.0794415416798357f)

typedef float f4v __attribute__((ext_vector_type(4)));
typedef __attribute__((address_space(3))) float as3f;

// async DMA global->LDS, 16B/lane, opaque to compiler (no auto waitcnt insertion)
__device__ __forceinline__ void dma16(unsigned ldsbyte, int voffbyte, const void* sbase) {
    asm volatile("s_mov_b32 m0, %0\n\t"
                 "global_load_lds_dwordx4 %1, %2"
                 :: "s"(ldsbyte), "v"(voffbyte), "s"(sbase)
                 : "memory");
}
// stores kept in asm: compiler does not track them -> no per-iter vmcnt drains
__device__ __forceinline__ void st16(void* p, f4v v) {
    asm volatile("global_store_dwordx4 %0, %1, off" :: "v"(p), "v"(v) : "memory");
}
// pinned LDS read: output lives in registers, cannot be rematerialized at use
__device__ __forceinline__ f4v ldsr16(int addr) {
    f4v out;
    asm volatile("ds_read_b128 %0, %1" : "=v"(out) : "v"(addr));
    return out;
}

// ---------------- Kernel A: gx tiled: W in regs, x tile in LDS --------------
// grid = B * (T/64) = 1024 blocks x 192 threads; thread = one output column g
// (dir = g/96). 64 rows per block; per row: 8 LDS broadcast f4 reads + 32 fma.
__global__ __launch_bounds__(192) void gx_kernel(
    const float* __restrict__ a_seq,
    const float* __restrict__ wih_f, const float* __restrict__ bih_f,
    const float* __restrict__ wih_b, const float* __restrict__ bih_b,
    float* __restrict__ gx) {
    __shared__ float xt[64 * 32];
    int blk = blockIdx.x;
    int b = blk >> 3;
    int t0 = (blk & 7) << 6;
    int g = threadIdx.x;            // 0..191
    int dir = (g >= 96) ? 1 : 0;
    int gg = dir ? (g - 96) : g;
    const float* w = dir ? wih_b : wih_f;
    const float* bv = dir ? bih_b : bih_f;

    // stage x tile [64][32] (coalesced float4)
    {
        const float4* src = (const float4*)(a_seq + ((size_t)b * T + t0) * PP);
        float4* dst = (float4*)xt;
        for (int idx = g; idx < 512; idx += 192) dst[idx] = src[idx];
    }
    float wreg[32];
#pragma unroll
    for (int q = 0; q < 8; ++q) {
        float4 wv = *(const float4*)(w + (size_t)gg * PP + q * 4);
        wreg[q * 4 + 0] = wv.x; wreg[q * 4 + 1] = wv.y;
        wreg[q * 4 + 2] = wv.z; wreg[q * 4 + 3] = wv.w;
    }
    float bias = bv[gg];
    __syncthreads();

    float* op = gx + ((size_t)(dir * B + b) * T + t0) * 96 + gg;
#pragma unroll 4
    for (int r = 0; r < 64; ++r) {
        const float4* xr = (const float4*)(xt + r * 32);
        float acc = bias;
#pragma unroll
        for (int q = 0; q < 8; ++q) {
            float4 xv = xr[q];
            acc = fmaf(xv.x, wreg[q * 4 + 0], acc);
            acc = fmaf(xv.y, wreg[q * 4 + 1], acc);
            acc = fmaf(xv.z, wreg[q * 4 + 2], acc);
            acc = fmaf(xv.w, wreg[q * 4 + 3], acc);
        }
        op[(size_t)r * 96] = acc;
    }
}

// ---------------- Kernel B: GRU scan, readlane-broadcast, no LDS ------------
__global__ __launch_bounds__(64) void gru_kernel(
    const float* __restrict__ gx,
    const float* __restrict__ whh_f, const float* __restrict__ bhh_f,
    const float* __restrict__ whh_b, const float* __restrict__ bhh_b,
    float* __restrict__ hseq) {
    int cid = blockIdx.x;            // 0..255 = dir*128 + b
    int b = cid & 127;
    int dir = cid >> 7;
    int l = threadIdx.x;
    int i = l & 31;
    const float* whh = dir ? whh_b : whh_f;
    const float* bhh = dir ? bhh_b : bhh_f;
    const float* gp0 = gx + (size_t)cid * (T * 96);

    float wr[32], wz[32], wn[32];
#pragma unroll
    for (int q = 0; q < 8; ++q) {
        float4 a0 = *(const float4*)(whh + (size_t)i * 32 + q * 4);
        float4 a1 = *(const float4*)(whh + (size_t)(32 + i) * 32 + q * 4);
        float4 a2 = *(const float4*)(whh + (size_t)(64 + i) * 32 + q * 4);
        wr[q * 4 + 0] = a0.x; wr[q * 4 + 1] = a0.y; wr[q * 4 + 2] = a0.z; wr[q * 4 + 3] = a0.w;
        wz[q * 4 + 0] = a1.x; wz[q * 4 + 1] = a1.y; wz[q * 4 + 2] = a1.z; wz[q * 4 + 3] = a1.w;
        wn[q * 4 + 0] = a2.x; wn[q * 4 + 1] = a2.y; wn[q * 4 + 2] = a2.z; wn[q * 4 + 3] = a2.w;
    }
    float bhr = bhh[i], bhz = bhh[32 + i], bhn = bhh[64 + i];

    const float* p = gp0 + (dir ? (T - 1) * 96 : 0);
    int gstep = dir ? -96 : 96;
    int voff = (((dir ? (T - 1) : 0) * B + b) * 64 + dir * 32 + i) * 4;
    int vstep = dir ? -(B * 64 * 4) : (B * 64 * 4);

    float pxr[8], pxz[8], pxn[8];
#pragma unroll
    for (int s = 0; s < 8; ++s) {
        const float* rp = p + s * gstep;
        pxr[s] = rp[i]; pxz[s] = rp[32 + i]; pxn[s] = rp[64 + i];
    }
    float h = 0.f;

#define GSTEP(SLOT) do {                                                       \
        float hr_ = pxr[SLOT] + bhr;                                           \
        float hz_ = pxz[SLOT] + bhz;                                           \
        float hn_ = bhn;                                                       \
        _Pragma("unroll")                                                      \
        for (int jj = 0; jj < 32; ++jj) {                                      \
            float hj_ = __uint_as_float(                                       \
                __builtin_amdgcn_readlane(__float_as_uint(h), jj));            \
            hr_ = fmaf(wr[jj], hj_, hr_);                                      \
            hz_ = fmaf(wz[jj], hj_, hz_);                                      \
            hn_ = fmaf(wn[jj], hj_, hn_);                                      \
        }                                                                      \
        float r_ = __builtin_amdgcn_rcpf(1.f + __expf(-hr_));                  \
        float z_ = __builtin_amdgcn_rcpf(1.f + __expf(-hz_));                  \
        float na_ = fmaf(r_, hn_, pxn[SLOT]);                                  \
        float e2_ = __expf(-2.f * fabsf(na_));                                 \
        float n_ = copysignf((1.f - e2_) * __builtin_amdgcn_rcpf(1.f + e2_), na_); \
        h = fmaf(z_, h - n_, n_);                                              \
        asm volatile("global_store_dword %0, %1, %2"                           \
                     :: "v"(voff), "v"(h), "s"(hseq) : "memory");              \
        voff += vstep;                                                         \
    } while (0)

    for (int tq = 0; tq < 64; ++tq) {
        GSTEP(0); GSTEP(1); GSTEP(2); GSTEP(3);
#pragma unroll
        for (int u = 0; u < 4; ++u) {
            int sc = tq * 8 + 8 + u; if (sc > T - 1) sc = T - 1;
            const float* rp = p + sc * gstep;
            pxr[u] = rp[i]; pxz[u] = rp[32 + i]; pxn[u] = rp[64 + i];
        }
        GSTEP(4); GSTEP(5); GSTEP(6); GSTEP(7);
#pragma unroll
        for (int u = 0; u < 4; ++u) {
            int sc = tq * 8 + 12 + u; if (sc > T - 1) sc = T - 1;
            const float* rp = p + sc * gstep;
            pxr[4 + u] = rp[i]; pxz[4 + u] = rp[32 + i]; pxn[4 + u] = rp[64 + i];
        }
    }
#undef GSTEP
}

// ---------------- Kernel C: logits' = (h_seq @ wl^T + bl) * (1/tau) ---------
__global__ __launch_bounds__(256) void logits_kernel(
    const float* __restrict__ hseq,
    const float* __restrict__ wl, const float* __restrict__ bl,
    const float* __restrict__ wi, const float* __restrict__ bi,
    float* __restrict__ logits, float* __restrict__ initl) {
    int q = threadIdx.x >> 6;
    int tb = blockIdx.x * 4 + q;   // t*B + b
    int g = threadIdx.x & 63;
    __shared__ float hrow[4][64];
    hrow[q][g] = hseq[(size_t)tb * 64 + g];
    __syncthreads();
    float acc = bl[g];
    const float* wrow = wl + (size_t)g * 64;
#pragma unroll
    for (int c = 0; c < 64; ++c) acc = fmaf(wrow[c], hrow[q][c], acc);
    logits[(size_t)tb * 64 + g] = acc * TINV;
    if (tb < B && g < 8) {            // t == 0 blocks, tb == b
        float a2 = bi[g];
        const float* w2 = wi + (size_t)g * 64;
#pragma unroll
        for (int c = 0; c < 64; ++c) a2 = fmaf(w2[c], hrow[q][c], a2);
        initl[tb * 8 + g] = a2;
    }
}

// ---------------- Kernel G: gumbel noise [t][b][8], pre-scaled by 1/tau -----
__global__ __launch_bounds__(256) void gsc_kernel(
    const float* __restrict__ u0, const float* __restrict__ useq,
    float* __restrict__ gs) {
    int id = blockIdx.x * 256 + threadIdx.x;
    if (id >= T * B * KK) return;
    int j = id & 7;
    int b = (id >> 3) & 127;
    int t = id >> 10;
    float u = (t == 0) ? u0[b * 8 + j]
                       : useq[((size_t)b * (T - 1) + (t - 1)) * 8 + j];
    gs[id] = -logf(-logf(u)) * TINV;   // precise logf: u near 1 is ill-conditioned
}

// ---------------- Kernel D: y-only scan, asm-DMA ring + asm-pinned reads ----
// EXACT round-5 structure (known-good): per phase 9 DMA + 2 asm stores = 11
// vm ops, uniform 11-op prologue, vmcnt(46) once then vmcnt(35) per phase.
__global__ __launch_bounds__(64, 1) void scan_kernel(
    const float* __restrict__ logits, const float* __restrict__ initl,
    const float* __restrict__ gs, float* __restrict__ yseq) {
    __shared__ float lds[6][2304];   // 6 slots x (32*64 logits + 32*8 gs)
    int r = threadIdx.x;
    int b0 = blockIdx.x * 32;
    int b = b0 + (r & 31);
    int k15 = r & 15;

    unsigned ldsU = (unsigned)(unsigned long long)(as3f*)(&lds[0][0]);

    // DMA source offsets, pre-swizzled with the same involution the reads use
    int lof[8];
#pragma unroll
    for (int q = 0; q < 8; ++q) {
        int rr = q * 4 + (r >> 4);         // tile row 0..31
        int cc = r & 15;                   // linear f4v col in LDS
        lof[q] = (((b0 + rr) * 64) + ((cc ^ (rr & 15)) << 2)) << 2;
    }
    int gof;
    {
        int rg = r >> 1;
        int cc = r & 1;
        gof = (((b0 + rg) * 8) + ((cc ^ (rg & 1)) << 2)) << 2;
    }
    unsigned rbase = ldsU + (unsigned)((r & 31) * 256);   // per-lane row base
    unsigned gbase = ldsU + 8192u + (unsigned)((r & 31) * 32);

#define ISSUE(tt, sl) do {                                                   \
        unsigned lb_ = ldsU + (unsigned)((sl) * 9216);                       \
        const char* bt_ = (const char*)logits + (size_t)(tt) * 32768;        \
        const char* gt_ = (const char*)gs + (size_t)(tt) * 4096;             \
        dma16(lb_ + 0 * 1024u, lof[0], bt_);                                 \
        dma16(lb_ + 1 * 1024u, lof[1], bt_);                                 \
        dma16(lb_ + 2 * 1024u, lof[2], bt_);                                 \
        dma16(lb_ + 3 * 1024u, lof[3], bt_);                                 \
        dma16(lb_ + 4 * 1024u, lof[4], bt_);                                 \
        dma16(lb_ + 5 * 1024u, lof[5], bt_);                                 \
        dma16(lb_ + 6 * 1024u, lof[6], bt_);                                 \
        dma16(lb_ + 7 * 1024u, lof[7], bt_);                                 \
        dma16(lb_ + 8192u, gof, gt_);                                        \
    } while (0)

#define SREAD(LL, GA, GB, tt) do {                                           \
        int so_ = ((tt) % 6) * 9216;                                         \
        _Pragma("unroll")                                                    \
        for (int m_ = 0; m_ < 16; ++m_)                                      \
            LL[m_] = ldsr16((int)(rbase + so_ + ((m_ ^ k15) << 4)));         \
        GA = ldsr16((int)(gbase + so_ + ((r & 1) << 4)));                    \
        GB = ldsr16((int)(gbase + so_ + (((r & 1) ^ 1) << 4)));              \
    } while (0)

#define LWAIT() do {                                                         \
        asm volatile("s_waitcnt lgkmcnt(0)" ::: "memory");                   \
        __builtin_amdgcn_sched_barrier(0);                                   \
    } while (0)

#define SCOMP(LL, GA, GB, tt) do {                                           \
        float a_[8] = {GA.x, GA.y, GA.z, GA.w, GB.x, GB.y, GB.z, GB.w};      \
        _Pragma("unroll")                                                    \
        for (int k_ = 0; k_ < 8; ++k_) {                                     \
            f4v w0_ = LL[2 * k_], w1_ = LL[2 * k_ + 1];                      \
            float yk_ = y[k_];                                               \
            a_[0] = fmaf(yk_, w0_.x, a_[0]); a_[1] = fmaf(yk_, w0_.y, a_[1]);\
            a_[2] = fmaf(yk_, w0_.z, a_[2]); a_[3] = fmaf(yk_, w0_.w, a_[3]);\
            a_[4] = fmaf(yk_, w1_.x, a_[4]); a_[5] = fmaf(yk_, w1_.y, a_[5]);\
            a_[6] = fmaf(yk_, w1_.z, a_[6]); a_[7] = fmaf(yk_, w1_.w, a_[7]);\
        }                                                                    \
        float m_ = fmaxf(fmaxf(fmaxf(a_[0], a_[1]), fmaxf(a_[2], a_[3])),    \
                         fmaxf(fmaxf(a_[4], a_[5]), fmaxf(a_[6], a_[7])));   \
        float ss_ = 0.f;                                                     \
        _Pragma("unroll")                                                    \
        for (int j_ = 0; j_ < 8; ++j_) { y[j_] = __expf(a_[j_] - m_); ss_ += y[j_]; } \
        float si_ = __builtin_amdgcn_rcpf(ss_);                              \
        _Pragma("unroll")                                                    \
        for (int j_ = 0; j_ < 8; ++j_) y[j_] *= si_;                         \
        if (r < 32) {                                                        \
            f4v v0_ = (f4v){y[0], y[1], y[2], y[3]};                         \
            f4v v1_ = (f4v){y[4], y[5], y[6], y[7]};                         \
            st16(&yp[2 * (tt)], v0_);                                        \
            st16(&yp[2 * (tt) + 1], v1_);                                    \
        }                                                                    \
    } while (0)

    f4v* yp = (f4v*)(yseq + (size_t)b * T * 8);
    float y[8];

    // ---- t = 0 from initl + gs[0] (plain loads, compiler-tracked) ----
    {
        const f4v* il4 = (const f4v*)(initl + b * 8);
        f4v i0 = il4[0], i1 = il4[1];
        const f4v* g4 = (const f4v*)(gs + b * 8);
        f4v G0 = g4[0], G1 = g4[1];
        float a[8];
        a[0] = fmaf(i0.x, TINV, G0.x); a[1] = fmaf(i0.y, TINV, G0.y);
        a[2] = fmaf(i0.z, TINV, G0.z); a[3] = fmaf(i0.w, TINV, G0.w);
        a[4] = fmaf(i1.x, TINV, G1.x); a[5] = fmaf(i1.y, TINV, G1.y);
        a[6] = fmaf(i1.z, TINV, G1.z); a[7] = fmaf(i1.w, TINV, G1.w);
        float m = fmaxf(fmaxf(fmaxf(a[0], a[1]), fmaxf(a[2], a[3])),
                        fmaxf(fmaxf(a[4], a[5]), fmaxf(a[6], a[7])));
        float ssum = 0.f;
#pragma unroll
        for (int j = 0; j < 8; ++j) { y[j] = __expf(a[j] - m); ssum += y[j]; }
        float sinv = __builtin_amdgcn_rcpf(ssum);
#pragma unroll
        for (int j = 0; j < 8; ++j) y[j] *= sinv;
    }
    f4v y0v = (f4v){y[0], y[1], y[2], y[3]};
    f4v y1v = (f4v){y[4], y[5], y[6], y[7]};

    // ---- prologue: 5 phases (ISSUE + 2 dup y0 stores) = uniform 11-op shape
#pragma unroll
    for (int p = 1; p <= 5; ++p) {
        ISSUE(p, p);
        if (r < 32) { st16(&yp[0], y0v); st16(&yp[1], y1v); }
    }

    f4v LA[16], LB[16], gaA, gbA, gaB, gbB;

    // slot 1 done when <=46 of the 55 prologue ops outstanding
    asm volatile("s_waitcnt vmcnt(46)" ::: "memory");
    __builtin_amdgcn_sched_barrier(0);
    SREAD(LA, gaA, gbA, 1);

    for (int t = 1; t < T - 1; t += 2) {
        asm volatile("s_waitcnt vmcnt(35)" ::: "memory");
        __builtin_amdgcn_sched_barrier(0);
        { int tp = t + 5; if (tp > T - 1) tp = T - 1; ISSUE(tp, (t + 5) % 6); }
        LWAIT();                       // LA (or prev LB) reads complete
        SREAD(LB, gaB, gbB, t + 1);
        SCOMP(LA, gaA, gbA, t);

        asm volatile("s_waitcnt vmcnt(35)" ::: "memory");
        __builtin_amdgcn_sched_barrier(0);
        { int tp = t + 6; if (tp > T - 1) tp = T - 1; ISSUE(tp, (t + 6) % 6); }
        LWAIT();
        SREAD(LA, gaA, gbA, t + 2);
        SCOMP(LB, gaB, gbB, t + 1);
    }
    LWAIT();
    SCOMP(LA, gaA, gbA, T - 1);
#undef ISSUE
#undef SREAD
#undef LWAIT
#undef SCOMP
}

// ---------------- Kernel E: parallel log_q / log_p --------------------------
__global__ __launch_bounds__(256) void lqlp_kernel(
    const float* __restrict__ logits, const float* __restrict__ initl,
    const float* __restrict__ yseq,
    float* __restrict__ logq, float* __restrict__ logp) {
    int tid = blockIdx.x * 256 + threadIdx.x;   // tid = b*T + t
    if (tid >= B * T) return;
    int b = tid >> 9;
    int t = tid & (T - 1);

    const float4* yt4 = (const float4*)(yseq + (size_t)tid * 8);
    float4 y0 = yt4[0], y1 = yt4[1];
    float yt[8] = {y0.x, y0.y, y0.z, y0.w, y1.x, y1.y, y1.z, y1.w};

    float l[8];
    float lp;
    if (t == 0) {
        const float4* il4 = (const float4*)(initl + b * 8);
        float4 i0 = il4[0], i1 = il4[1];
        l[0] = i0.x; l[1] = i0.y; l[2] = i0.z; l[3] = i0.w;
        l[4] = i1.x; l[5] = i1.y; l[6] = i1.z; l[7] = i1.w;
        float sy = ((yt[0] + yt[1]) + (yt[2] + yt[3])) + ((yt[4] + yt[5]) + (yt[6] + yt[7]));
        lp = LOG_INV_K * sy;
    } else {
        const float4* yp4 = (const float4*)(yseq + (size_t)tid * 8 - 8);
        float4 p0 = yp4[0], p1 = yp4[1];
        float ypv[8] = {p0.x, p0.y, p0.z, p0.w, p1.x, p1.y, p1.z, p1.w};
        const float4* L4 = (const float4*)(logits + ((size_t)t * B + b) * 64);
#pragma unroll
        for (int j = 0; j < 8; ++j) l[j] = 0.f;
#pragma unroll
        for (int k = 0; k < 8; ++k) {
            float4 w0 = L4[2 * k], w1 = L4[2 * k + 1];
            float yk = ypv[k];
            l[0] = fmaf(yk, w0.x, l[0]); l[1] = fmaf(yk, w0.y, l[1]);
            l[2] = fmaf(yk, w0.z, l[2]); l[3] = fmaf(yk, w0.w, l[3]);
            l[4] = fmaf(yk, w1.x, l[4]); l[5] = fmaf(yk, w1.y, l[5]);
            l[6] = fmaf(yk, w1.z, l[6]); l[7] = fmaf(yk, w1.w, l[7]);
        }
#pragma unroll
        for (int j = 0; j < 8; ++j) l[j] *= 0.5f;   // stored logits are pre-scaled by 1/tau
        float sy = ((ypv[0] + ypv[1]) + (ypv[2] + ypv[3])) + ((ypv[4] + ypv[5]) + (ypv[6] + ypv[7]));
        float acc = 0.f;
#pragma unroll
        for (int j = 0; j < 8; ++j) {
            float tp = fmaf(DPS, ypv[j], OFFV * sy);
            acc = fmaf(yt[j], logf(fmaxf(tp, 1e-8f)), acc);
        }
        lp = acc;
    }
    float m = fmaxf(fmaxf(fmaxf(l[0], l[1]), fmaxf(l[2], l[3])),
                    fmaxf(fmaxf(l[4], l[5]), fmaxf(l[6], l[7])));
    float se = 0.f;
#pragma unroll
    for (int j = 0; j < 8; ++j) se += __expf(l[j] - m);
    float lse = m + logf(se);
    float lq = 0.f;
#pragma unroll
    for (int j = 0; j < 8; ++j) lq = fmaf(yt[j], l[j] - lse, lq);
    logq[tid] = lq;
    logp[tid] = lp;
}

// ---------------- Kernel F: output einsums + C broadcast (float4 stores) ----
__global__ __launch_bounds__(128) void out_kernel(
    const float* __restrict__ yseq,
    const float* __restrict__ A, const float* __restrict__ Bm,
    const float* __restrict__ C, const float* __restrict__ Q,
    float4* __restrict__ out4) {
    int bt = blockIdx.x;   // b*T + t
    __shared__ float ys[8];
    if (threadIdx.x < 8) ys[threadIdx.x] = yseq[(size_t)bt * 8 + threadIdx.x];
    __syncthreads();
    float yr[8];
#pragma unroll
    for (int k = 0; k < 8; ++k) yr[k] = ys[k];

    const float4* A4 = (const float4*)A;
    const float4* B4 = (const float4*)Bm;
    const float4* Q4 = (const float4*)Q;
    const float4* C4 = (const float4*)C;

    for (int q = threadIdx.x; q < 288; q += 128) {
        float4 v = make_float4(0.f, 0.f, 0.f, 0.f);
        size_t oidx;
        if (q < 64) {
#pragma unroll
            for (int k = 0; k < 8; ++k) {
                float4 w = A4[k * 64 + q];
                v.x = fmaf(yr[k], w.x, v.x);
                v.y = fmaf(yr[k], w.y, v.y);
                v.z = fmaf(yr[k], w.z, v.z);
                v.w = fmaf(yr[k], w.w, v.w);
            }
            oidx = (size_t)(OUT_A / 4) + (size_t)bt * 64 + q;
        } else if (q < 96) {
            int qb = q - 64;
#pragma unroll
            for (int k = 0; k < 8; ++k) {
                float4 w = B4[k * 32 + qb];
                v.x = fmaf(yr[k], w.x, v.x);
                v.y = fmaf(yr[k], w.y, v.y);
                v.z = fmaf(yr[k], w.z, v.z);
                v.w = fmaf(yr[k], w.w, v.w);
            }
            oidx = (size_t)(OUT_B / 4) + (size_t)bt * 32 + qb;
        } else if (q < 160) {
            int qq = q - 96;
#pragma unroll
            for (int k = 0; k < 8; ++k) {
                float4 w = Q4[k * 64 + qq];
                v.x = fmaf(yr[k], w.x, v.x);
                v.y = fmaf(yr[k], w.y, v.y);
                v.z = fmaf(yr[k], w.z, v.z);
                v.w = fmaf(yr[k], w.w, v.w);
            }
            oidx = (size_t)(OUT_Q / 4) + (size_t)bt * 64 + qq;
        } else {
            int qc = q - 160;
            v = C4[qc];
            oidx = (size_t)(OUT_C / 4) + (size_t)bt * 128 + qc;
        }
        out4[oidx] = v;
    }
}

extern "C" void kernel_launch(void* const* d_in, const int* in_sizes, int n_in,
                              void* d_out, int out_size, void* d_ws, size_t ws_size,
                              hipStream_t stream) {
    const float* a_seq = (const float*)d_in[0];
    const float* A     = (const float*)d_in[1];
    const float* Bmat  = (const float*)d_in[2];
    const float* C     = (const float*)d_in[3];
    const float* Q     = (const float*)d_in[4];
    const float* wih_f = (const float*)d_in[5];
    const float* whh_f = (const float*)d_in[6];
    const float* bih_f = (const float*)d_in[7];
    const float* bhh_f = (const float*)d_in[8];
    const float* wih_b = (const float*)d_in[9];
    const float* whh_b = (const float*)d_in[10];
    const float* bih_b = (const float*)d_in[11];
    const float* bhh_b = (const float*)d_in[12];
    const float* wl    = (const float*)d_in[13];
    const float* bl    = (const float*)d_in[14];
    const float* wi    = (const float*)d_in[15];
    const float* bi    = (const float*)d_in[16];
    const float* u0    = (const float*)d_in[17];
    const float* useq  = (const float*)d_in[18];

    float* ws = (float*)d_ws;
    float* gx     = ws + WS_GX;
    float* gsb    = ws + WS_GS;       // aliases gx dir=1 half (written after GRU)
    float* hseq   = ws + WS_HSEQ;
    float* logits = ws + WS_LOGITS;   // aliases gx dir=0 half (written after GRU)
    float* initl  = ws + WS_INIT;
    float* yseq   = ws + WS_YSEQ;

    float* outf = (float*)d_out;
    float* logq = outf + OUT_LQ;
    float* logp = outf + OUT_LP;

    gx_kernel<<<B * (T / 64), 192, 0, stream>>>(a_seq, wih_f, bih_f, wih_b, bih_b, gx);
    gru_kernel<<<256, 64, 0, stream>>>(gx, whh_f, bhh_f, whh_b, bhh_b, hseq);
    {
        int total = B * T * KK;
        gsc_kernel<<<(total + 255) / 256, 256, 0, stream>>>(u0, useq, gsb);
    }
    logits_kernel<<<T * B / 4, 256, 0, stream>>>(hseq, wl, bl, wi, bi, logits, initl);
    scan_kernel<<<4, 64, 0, stream>>>(logits, initl, gsb, yseq);
    lqlp_kernel<<<(B * T + 255) / 256, 256, 0, stream>>>(logits, initl, yseq, logq, logp);
    out_kernel<<<B * T, 128, 0, stream>>>(yseq, A, Bmat, C, Q, (float4*)d_out);
}